// Round 1
// baseline (929.429 us; speedup 1.0000x reference)
//
#include <hip/hip_runtime.h>

// Linear attention (B=8, T=2048, D=512), fp32 chunked formulation.
// R1: correctness-first fp32 vector GEMMs (no MFMA). ~60 GFLOP total.
//
// chunked math (C=256, NC=8):
//   q=phi(xWq), k=phi(xWk), v=xWv          (k_qkv)
//   zpre[b,c,:]  = sum_{t < c*C} k_t        (k_zpre_part + k_zpre_scan, in place)
//   G[b,c]       = tril(Q_c K_c^T)          (k_G; upper tiles zeroed via memset)
//   den[b,t]     = q_t.zpre + rowsum(G)+eps (k_den)
//   M_c          = K_c^T V_c                (k_M)
//   S_c          = exclusive prefix of M    (k_prefix, in place)
//   y_c          = (Q_c S_c + G_c V_c)/den  (k_y, writes into k's buffer)
//   out          = y Wp                     (k_out)

#define EPSV 1e-6f

constexpr int B = 8, T = 2048, D = 512;
constexpr int CHK = 256, NC = T / CHK;   // 8 chunks of 256
constexpr int KST = 16;                  // GEMM k-step
constexpr int LDSP = 68;                 // padded LDS stride (64+4)

constexpr size_t SZ_BTD = (size_t)B * T * D;            // 8.39M floats
constexpr size_t OFF_Q   = 0;
constexpr size_t OFF_K   = OFF_Q + SZ_BTD;              // reused as Y after scan
constexpr size_t OFF_V   = OFF_K + SZ_BTD;
constexpr size_t OFF_G   = OFF_V + SZ_BTD;
constexpr size_t SZ_G    = (size_t)B * NC * CHK * CHK;  // 4.19M
constexpr size_t OFF_MS  = OFF_G + SZ_G;
constexpr size_t SZ_MS   = (size_t)B * NC * D * D;      // 16.78M
constexpr size_t OFF_ZP  = OFF_MS + SZ_MS;              // B*NC*D
constexpr size_t OFF_DEN = OFF_ZP + (size_t)B * NC * D; // B*T
constexpr size_t WS_NEED = (OFF_DEN + (size_t)B * T) * sizeof(float); // ~185 MB

// ---- shared GEMM building blocks: 64x64 tile, 256 threads, 4x4 per thread ----

// Stage A-tile (row-major M x K operand): rows m0..m0+63, cols k0..k0+15,
// transposed into As[kk][m]. float4 global load, 2-way (free) LDS write conflict.
__device__ __forceinline__ void stage_A(const float* __restrict__ A, int lda, int m0, int k0,
                                        float (*As)[LDSP], int tid) {
  int row = tid >> 2, c4 = (tid & 3) << 2;
  float4 f = *(const float4*)(A + (size_t)(m0 + row) * lda + k0 + c4);
  As[c4 + 0][row] = f.x;
  As[c4 + 1][row] = f.y;
  As[c4 + 2][row] = f.z;
  As[c4 + 3][row] = f.w;
}

// Stage B-tile (row-major K x N operand): rows k0..k0+15, cols n0..n0+63 into Bs[kk][n].
__device__ __forceinline__ void stage_B(const float* __restrict__ Bp, int ldb, int k0, int n0,
                                        float (*Bs)[LDSP], int tid) {
  int row = tid >> 4, c4 = (tid & 15) << 2;
  float4 f = *(const float4*)(Bp + (size_t)(k0 + row) * ldb + n0 + c4);
  *(float4*)&Bs[row][c4] = f;
}

__device__ __forceinline__ void mm_step(const float (*As)[LDSP], const float (*Bs)[LDSP],
                                        float acc[4][4], int tx, int ty) {
#pragma unroll
  for (int kk = 0; kk < KST; ++kk) {
    float4 a = *(const float4*)&As[kk][ty << 2];
    float4 b = *(const float4*)&Bs[kk][tx << 2];
    float av[4] = {a.x, a.y, a.z, a.w};
    float bv[4] = {b.x, b.y, b.z, b.w};
#pragma unroll
    for (int i = 0; i < 4; ++i)
#pragma unroll
      for (int j = 0; j < 4; ++j)
        acc[i][j] = fmaf(av[i], bv[j], acc[i][j]);
  }
}

// ---- kernel 1: q = phi(xWq), k = phi(xWk), v = xWv ----
__global__ __launch_bounds__(256) void k_qkv(const float* __restrict__ x,
                                             const float* __restrict__ Wq,
                                             const float* __restrict__ Wk,
                                             const float* __restrict__ Wv,
                                             float* __restrict__ ws) {
  __shared__ float As[KST][LDSP], Bs[KST][LDSP];
  int tid = threadIdx.x, tx = tid & 15, ty = tid >> 4;
  int m0 = blockIdx.x * 64, n0 = blockIdx.y * 64, which = blockIdx.z;
  const float* W = (which == 0) ? Wq : ((which == 1) ? Wk : Wv);
  float* out = ws + ((which == 0) ? OFF_Q : ((which == 1) ? OFF_K : OFF_V));
  float acc[4][4] = {};
  for (int k0 = 0; k0 < D; k0 += KST) {
    __syncthreads();
    stage_A(x, D, m0, k0, As, tid);
    stage_B(W, D, k0, n0, Bs, tid);
    __syncthreads();
    mm_step(As, Bs, acc, tx, ty);
  }
  bool phi = (which < 2);
#pragma unroll
  for (int i = 0; i < 4; ++i) {
    float o[4];
#pragma unroll
    for (int j = 0; j < 4; ++j) {
      float vv = acc[i][j];
      o[j] = phi ? (vv > 0.f ? vv + 1.f : __expf(vv)) : vv;
    }
    *(float4*)&out[(size_t)(m0 + (ty << 2) + i) * D + n0 + (tx << 2)] =
        make_float4(o[0], o[1], o[2], o[3]);
  }
}

// ---- kernel 2a: per-chunk column sums of k -> zpre buffer (chunk sums) ----
__global__ __launch_bounds__(256) void k_zpre_part(float* __restrict__ ws) {
  int d = blockIdx.x * 256 + threadIdx.x;  // gridDim.x==2 -> d in 0..511
  int c = blockIdx.y, b = blockIdx.z;
  const float* kp = ws + OFF_K + ((size_t)(b * T + c * CHK)) * D + d;
  float s = 0.f;
#pragma unroll 8
  for (int t = 0; t < CHK; ++t) s += kp[(size_t)t * D];
  ws[OFF_ZP + (size_t)(b * NC + c) * D + d] = s;
}

// ---- kernel 2b: in-place exclusive prefix over chunks ----
__global__ __launch_bounds__(256) void k_zpre_scan(float* __restrict__ ws) {
  int gid = blockIdx.x * 256 + threadIdx.x;  // 0..4095
  int b = gid >> 9, d = gid & 511;
  float acc = 0.f;
#pragma unroll
  for (int c = 0; c < NC; ++c) {
    size_t idx = OFF_ZP + (size_t)(b * NC + c) * D + d;
    float t = ws[idx];
    ws[idx] = acc;
    acc += t;
  }
}

// ---- kernel 3: G = tril(Q_c K_c^T), lower/diag 64x64 tiles only ----
__global__ __launch_bounds__(256) void k_G(float* __restrict__ ws) {
  __shared__ float As[KST][LDSP], Bs[KST][LDSP];
  const int TIa[10] = {0, 1, 1, 2, 2, 2, 3, 3, 3, 3};
  const int TJa[10] = {0, 0, 1, 0, 1, 2, 0, 1, 2, 3};
  int tid = threadIdx.x, tx = tid & 15, ty = tid >> 4;
  int tile = blockIdx.x, bc = blockIdx.y;  // 10 x 64
  int b = bc >> 3, c = bc & 7;
  int ti = TIa[tile], tj = TJa[tile];
  const float* Q = ws + OFF_Q + (size_t)(b * T + c * CHK) * D;
  const float* Kp = ws + OFF_K + (size_t)(b * T + c * CHK) * D;
  float* G = ws + OFF_G + (size_t)bc * CHK * CHK;
  float acc[4][4] = {};
  for (int k0 = 0; k0 < D; k0 += KST) {
    __syncthreads();
    stage_A(Q, D, ti * 64, k0, As, tid);
    stage_A(Kp, D, tj * 64, k0, Bs, tid);  // B[d][s] = K[s][d] -> same staging pattern
    __syncthreads();
    mm_step(As, Bs, acc, tx, ty);
  }
#pragma unroll
  for (int i = 0; i < 4; ++i) {
    int t = ti * 64 + (ty << 2) + i;
    float o[4];
#pragma unroll
    for (int j = 0; j < 4; ++j) {
      int s = tj * 64 + (tx << 2) + j;
      o[j] = (s <= t) ? acc[i][j] : 0.f;
    }
    *(float4*)&G[(size_t)t * CHK + tj * 64 + (tx << 2)] = make_float4(o[0], o[1], o[2], o[3]);
  }
}

// ---- kernel 4: den[b,t] = q_t . zpre + rowsum(G row) + eps ----
__global__ __launch_bounds__(256) void k_den(float* __restrict__ ws) {
  int widx = threadIdx.x >> 6, lane = threadIdx.x & 63;
  int bt = blockIdx.x * 4 + widx;
  int b = bt >> 11, t = bt & 2047;
  int c = t >> 8, tl = t & 255;
  const float* q = ws + OFF_Q + (size_t)bt * D;
  const float* zp = ws + OFF_ZP + (size_t)(b * NC + c) * D;
  const float* Grow = ws + OFF_G + (size_t)(b * NC + c) * CHK * CHK + (size_t)tl * CHK;
  float s = 0.f;
#pragma unroll
  for (int i = 0; i < 8; ++i) {
    int d = lane + 64 * i;
    s = fmaf(q[d], zp[d], s);
  }
#pragma unroll
  for (int i = 0; i < 4; ++i) s += Grow[lane + 64 * i];  // upper part is zero
#pragma unroll
  for (int off = 32; off >= 1; off >>= 1) s += __shfl_xor(s, off, 64);
  if (lane == 0) ws[OFF_DEN + bt] = s + EPSV;
}

// ---- kernel 5: M_c = K_c^T V_c ----
__global__ __launch_bounds__(256) void k_M(float* __restrict__ ws) {
  __shared__ float As[KST][LDSP], Bs[KST][LDSP];
  int tid = threadIdx.x, tx = tid & 15, ty = tid >> 4;
  int m0 = blockIdx.x * 64, n0 = blockIdx.y * 64, bc = blockIdx.z;
  int b = bc >> 3, c = bc & 7;
  const float* Kp = ws + OFF_K + (size_t)(b * T + c * CHK) * D;
  const float* V = ws + OFF_V + (size_t)(b * T + c * CHK) * D;
  float* M = ws + OFF_MS + (size_t)bc * D * D;
  float acc[4][4] = {};
  for (int t0 = 0; t0 < CHK; t0 += KST) {
    __syncthreads();
    stage_B(Kp, D, t0, m0, As, tid);  // As[t][m] = K[t][m] (t is reduction dim)
    stage_B(V, D, t0, n0, Bs, tid);
    __syncthreads();
    mm_step(As, Bs, acc, tx, ty);
  }
#pragma unroll
  for (int i = 0; i < 4; ++i)
    *(float4*)&M[(size_t)(m0 + (ty << 2) + i) * D + n0 + (tx << 2)] =
        make_float4(acc[i][0], acc[i][1], acc[i][2], acc[i][3]);
}

// ---- kernel 6: in-place exclusive prefix of M over chunks -> S_c ----
__global__ __launch_bounds__(256) void k_prefix(float* __restrict__ ws) {
  int b = blockIdx.x >> 8, blk = blockIdx.x & 255;
  size_t base = OFF_MS + (size_t)b * NC * D * D + (size_t)blk * 1024 + (size_t)threadIdx.x * 4;
  float4 acc = make_float4(0.f, 0.f, 0.f, 0.f);
#pragma unroll
  for (int c = 0; c < NC; ++c) {
    float4* p = (float4*)(ws + base + (size_t)c * D * D);
    float4 t = *p;
    *p = acc;
    acc.x += t.x; acc.y += t.y; acc.z += t.z; acc.w += t.w;
  }
}

// ---- kernel 7: y_c = (Q_c S_c + G_c V_c) / den, write into K's buffer ----
__global__ __launch_bounds__(256) void k_y(float* __restrict__ ws) {
  __shared__ float As[KST][LDSP], Bs[KST][LDSP];
  int tid = threadIdx.x, tx = tid & 15, ty = tid >> 4;
  int t0 = blockIdx.x * 64, n0 = blockIdx.y * 64, bc = blockIdx.z;
  int b = bc >> 3, c = bc & 7;
  const float* Q = ws + OFF_Q + (size_t)(b * T + c * CHK) * D;
  const float* S = ws + OFF_MS + (size_t)bc * D * D;
  const float* G = ws + OFF_G + (size_t)bc * CHK * CHK;
  const float* V = ws + OFF_V + (size_t)(b * T + c * CHK) * D;
  const float* den = ws + OFF_DEN + (size_t)(b * T + c * CHK);
  float* Y = ws + OFF_K + (size_t)(b * T + c * CHK) * D;
  float acc[4][4] = {};
  for (int k0 = 0; k0 < D; k0 += KST) {  // inter-chunk: Q_c @ S_c
    __syncthreads();
    stage_A(Q, D, t0, k0, As, tid);
    stage_B(S, D, k0, n0, Bs, tid);
    __syncthreads();
    mm_step(As, Bs, acc, tx, ty);
  }
  for (int k0 = 0; k0 < CHK; k0 += KST) {  // intra-chunk: G_c @ V_c (G masked)
    __syncthreads();
    stage_A(G, CHK, t0, k0, As, tid);
    stage_B(V, D, k0, n0, Bs, tid);
    __syncthreads();
    mm_step(As, Bs, acc, tx, ty);
  }
#pragma unroll
  for (int i = 0; i < 4; ++i) {
    int tl = t0 + (ty << 2) + i;
    float dinv = 1.f / den[tl];
    *(float4*)&Y[(size_t)tl * D + n0 + (tx << 2)] =
        make_float4(acc[i][0] * dinv, acc[i][1] * dinv, acc[i][2] * dinv, acc[i][3] * dinv);
  }
}

// ---- kernel 8: out = y @ Wp ----
__global__ __launch_bounds__(256) void k_out(const float* __restrict__ Wp,
                                             float* __restrict__ ws, float* __restrict__ out) {
  __shared__ float As[KST][LDSP], Bs[KST][LDSP];
  int tid = threadIdx.x, tx = tid & 15, ty = tid >> 4;
  int m0 = blockIdx.x * 64, n0 = blockIdx.y * 64;
  const float* Y = ws + OFF_K;
  float acc[4][4] = {};
  for (int k0 = 0; k0 < D; k0 += KST) {
    __syncthreads();
    stage_A(Y, D, m0, k0, As, tid);
    stage_B(Wp, D, k0, n0, Bs, tid);
    __syncthreads();
    mm_step(As, Bs, acc, tx, ty);
  }
#pragma unroll
  for (int i = 0; i < 4; ++i)
    *(float4*)&out[(size_t)(m0 + (ty << 2) + i) * D + n0 + (tx << 2)] =
        make_float4(acc[i][0], acc[i][1], acc[i][2], acc[i][3]);
}

extern "C" void kernel_launch(void* const* d_in, const int* in_sizes, int n_in,
                              void* d_out, int out_size, void* d_ws, size_t ws_size,
                              hipStream_t stream) {
  const float* x  = (const float*)d_in[0];
  const float* Wq = (const float*)d_in[1];
  const float* Wk = (const float*)d_in[2];
  const float* Wv = (const float*)d_in[3];
  const float* Wp = (const float*)d_in[4];
  float* ws = (float*)d_ws;
  float* out = (float*)d_out;

  if (ws_size < WS_NEED) return;  // scratch too small: fail validation visibly, not a fault

  // zero G so the skipped strictly-upper tiles read as 0 in k_den / k_y
  hipMemsetAsync(ws + OFF_G, 0, SZ_G * sizeof(float), stream);

  k_qkv<<<dim3(T * B / 64, D / 64, 3), 256, 0, stream>>>(x, Wq, Wk, Wv, ws);
  k_zpre_part<<<dim3(2, NC, B), 256, 0, stream>>>(ws);
  k_zpre_scan<<<dim3(16), 256, 0, stream>>>(ws);
  k_G<<<dim3(10, B * NC), 256, 0, stream>>>(ws);
  k_den<<<dim3(B * T / 4), 256, 0, stream>>>(ws);
  k_M<<<dim3(D / 64, D / 64, B * NC), 256, 0, stream>>>(ws);
  k_prefix<<<dim3(B * 256), 256, 0, stream>>>(ws);
  k_y<<<dim3(CHK / 64, D / 64, B * NC), 256, 0, stream>>>(ws);
  k_out<<<dim3(T * B / 64, D / 64), 256, 0, stream>>>(Wp, ws, out);
}

// Round 2
// 208.389 us; speedup vs baseline: 4.4601x; 4.4601x over previous
//
#include <hip/hip_runtime.h>

// Linear attention (B=8, T=2048, D=512), chunked, bf16 MFMA (16x16x32), fp32 acc.
// All GEMMs are C = A * B^T with A:[M][K], B:[N][K] row-major bf16 (m97 structure).
//
//   xb   = bf16(x)                                   k_conv_x
//   WT   = bf16(W^T) for Wq,Wk,Wv,Wp                 k_wt
//   q    = phi(xb . WqT^T)   [16384][512]            k_gemm<1>
//   kk   = phi(xb . WkT^T)   [16384][512]            k_gemm<1>
//   Kt   = phi(WkT . xb^T)   [512][16384]            k_gemm<1>
//   Vt   =     WvT . xb^T    [512][16384]            k_gemm<0>
//   zp   = chunk sums of kk, exclusive-scanned       k_zsum, k_zscan
//   G    = tril(Q_c K_c^T)   [64][256][256]          k_gemm_G (3 tiles/chunk)
//   den  = q.zp + rowsum(G) + eps                    k_den
//   Mt   = Vt_c . Kt_c^T     [64][512][512]          k_gemm_M   (Mt = (K^T V)^T)
//   St   = exclusive chunk prefix of Mt (in place)   k_prefix
//   y    = (Q_c St_c^T + G_c Vt_c^T) / den           k_gemm_y
//   out  = y . WpT^T  (fp32)                         k_gemm<2>

typedef __attribute__((ext_vector_type(4))) float f32x4;
typedef __attribute__((ext_vector_type(8))) __bf16 bf16x8;
typedef __attribute__((ext_vector_type(8))) unsigned short ushort8;

// ---- ws layout (byte offsets) ----
constexpr size_t OFF_XB  = 0;                  // bf16 [16384][512]
constexpr size_t OFF_WT  = OFF_XB + 16777216;  // bf16 4x [512][512] (WqT,WkT,WvT,WpT)
constexpr size_t OFF_Q   = OFF_WT + 2097152;   // bf16 [16384][512]
constexpr size_t OFF_KK  = OFF_Q  + 16777216;  // bf16 [16384][512]
constexpr size_t OFF_KT  = OFF_KK + 16777216;  // bf16 [512][16384]
constexpr size_t OFF_VT  = OFF_KT + 16777216;  // bf16 [512][16384]
constexpr size_t OFF_G   = OFF_VT + 16777216;  // bf16 [64][256][256]
constexpr size_t OFF_MT  = OFF_G  + 8388608;   // bf16 [64][512][512] (becomes St)
constexpr size_t OFF_Y   = OFF_MT + 33554432;  // bf16 [16384][512]
constexpr size_t OFF_ZP  = OFF_Y  + 16777216;  // f32  [64][512]
constexpr size_t OFF_DEN = OFF_ZP + 131072;    // f32  [16384]
constexpr size_t WS_NEED = OFF_DEN + 65536;    // ~138.2 MB

__device__ __forceinline__ unsigned short bfbits(float f) {
  __bf16 h = (__bf16)f;
  return __builtin_bit_cast(unsigned short, h);
}
__device__ __forceinline__ float bff(unsigned short u) {
  return (float)__builtin_bit_cast(__bf16, u);
}

__device__ __forceinline__ void gload16(const void* g, void* l) {
  __builtin_amdgcn_global_load_lds((const __attribute__((address_space(1))) void*)g,
                                   (__attribute__((address_space(3))) void*)l, 16, 0, 0);
}

// ---- core: accumulate a 128x128 C-tile of A(MxK) * B^T (B: NxK), both bf16 row-major.
// 256 threads = 4 waves in 2x2; each wave 64x64 = 4x4 frags of 16x16. BK=32 per step.
__device__ __forceinline__ void gemm_core(const ushort* __restrict__ A, int lda,
                                          const ushort* __restrict__ B, int ldb,
                                          int ksteps, ushort* As, ushort* Bs,
                                          f32x4 acc[4][4]) {
  const int tid = (int)threadIdx.x;
  const int w = tid >> 6, l = tid & 63;
  const int wr = w >> 1, wc = w & 1;
  const int srow = (w << 5) + (l >> 2);   // staging row (chunk 0), wave w owns rows w*32..+31
  const int scol = (l & 3) << 3;          // staging col (elems)
  const ushort* ga = A + (size_t)srow * lda + scol;
  const ushort* gb = B + (size_t)srow * ldb + scol;
  ushort* lA0 = As + (w << 10);           // wave-uniform LDS bases
  ushort* lA1 = As + (w << 10) + 512;
  ushort* lB0 = Bs + (w << 10);
  ushort* lB1 = Bs + (w << 10) + 512;
  const int fr = l & 15, fk = (l >> 4) << 3;

  for (int s = 0; s < ksteps; ++s) {
    __syncthreads();  // previous step's LDS reads done
    const ushort* gao = ga + s * 32;
    const ushort* gbo = gb + s * 32;
    gload16(gao, lA0);
    gload16(gao + (size_t)16 * lda, lA1);
    gload16(gbo, lB0);
    gload16(gbo + (size_t)16 * ldb, lB1);
    __syncthreads();  // compiler drains vmcnt before barrier
    bf16x8 af[4], bg[4];
#pragma unroll
    for (int m = 0; m < 4; ++m)
      af[m] = *(const bf16x8*)&As[(((wr << 6) + (m << 4) + fr) << 5) + fk];
#pragma unroll
    for (int n = 0; n < 4; ++n)
      bg[n] = *(const bf16x8*)&Bs[(((wc << 6) + (n << 4) + fr) << 5) + fk];
#pragma unroll
    for (int m = 0; m < 4; ++m)
#pragma unroll
      for (int n = 0; n < 4; ++n)
        acc[m][n] = __builtin_amdgcn_mfma_f32_16x16x32_bf16(af[m], bg[n], acc[m][n], 0, 0, 0);
  }
}

#define ACC_INIT                                   \
  f32x4 acc[4][4];                                 \
  _Pragma("unroll") for (int m_ = 0; m_ < 4; ++m_) \
  _Pragma("unroll") for (int n_ = 0; n_ < 4; ++n_) \
      acc[m_][n_] = f32x4{0.f, 0.f, 0.f, 0.f};

// ---- generic GEMM: EPI 0 = bf16 store, 1 = phi + bf16, 2 = fp32 store ----
template <int EPI>
__global__ __launch_bounds__(256) void k_gemm(const ushort* __restrict__ A, int lda,
                                              const ushort* __restrict__ B, int ldb,
                                              void* __restrict__ Cv, int ldc, int ksteps) {
  __shared__ __align__(16) ushort As[4096], Bs[4096];
  ACC_INIT
  gemm_core(A + (size_t)blockIdx.x * 128 * lda, lda,
            B + (size_t)blockIdx.y * 128 * ldb, ldb, ksteps, As, Bs, acc);
  const int tid = (int)threadIdx.x, w = tid >> 6, l = tid & 63;
  const int wr = w >> 1, wc = w & 1;
  const size_t row0 = (size_t)blockIdx.x * 128 + (wr << 6) + ((l >> 4) << 2);
  const size_t col0 = (size_t)blockIdx.y * 128 + (wc << 6) + (l & 15);
#pragma unroll
  for (int m = 0; m < 4; ++m)
#pragma unroll
    for (int n = 0; n < 4; ++n)
#pragma unroll
      for (int r = 0; r < 4; ++r) {
        float v = acc[m][n][r];
        if (EPI == 1) v = (v > 0.f) ? v + 1.f : __expf(v);
        size_t row = row0 + (m << 4) + r, col = col0 + (n << 4);
        if (EPI == 2) ((float*)Cv)[row * ldc + col] = v;
        else ((ushort*)Cv)[row * ldc + col] = bfbits(v);
      }
}

// ---- G = tril(Q_c K_c^T): 3 tiles per chunk: 0:(0,0) 1:(1,0) 2:(1,1) ----
__global__ __launch_bounds__(256) void k_gemm_G(const ushort* __restrict__ q,
                                                const ushort* __restrict__ kk,
                                                ushort* __restrict__ G) {
  __shared__ __align__(16) ushort As[4096], Bs[4096];
  const int tile = blockIdx.x;
  const int ti = (tile == 0) ? 0 : 1, tj = (tile == 2) ? 1 : 0;
  const int bc = blockIdx.y;
  ACC_INIT
  gemm_core(q + (size_t)bc * 131072 + (size_t)ti * 128 * 512, 512,
            kk + (size_t)bc * 131072 + (size_t)tj * 128 * 512, 512, 16, As, Bs, acc);
  ushort* Gc = G + (size_t)bc * 65536;
  const int tid = (int)threadIdx.x, w = tid >> 6, l = tid & 63;
  const int wr = w >> 1, wc = w & 1;
  const int rbase = ti * 128 + (wr << 6) + ((l >> 4) << 2);
  const int cbase = tj * 128 + (wc << 6) + (l & 15);
#pragma unroll
  for (int m = 0; m < 4; ++m)
#pragma unroll
    for (int n = 0; n < 4; ++n)
#pragma unroll
      for (int r = 0; r < 4; ++r) {
        int row = rbase + (m << 4) + r, col = cbase + (n << 4);
        float v = (col <= row) ? acc[m][n][r] : 0.f;
        Gc[(size_t)row * 256 + col] = bfbits(v);
      }
}

// ---- Mt_c = Vt_c . Kt_c^T  ([e][d], K over t=256) ----
__global__ __launch_bounds__(256) void k_gemm_M(const ushort* __restrict__ Kt,
                                                const ushort* __restrict__ Vt,
                                                ushort* __restrict__ Mt) {
  __shared__ __align__(16) ushort As[4096], Bs[4096];
  const int bc = blockIdx.z;
  ACC_INIT
  gemm_core(Vt + (size_t)blockIdx.x * 128 * 16384 + (size_t)bc * 256, 16384,
            Kt + (size_t)blockIdx.y * 128 * 16384 + (size_t)bc * 256, 16384, 8, As, Bs, acc);
  ushort* Mc = Mt + (size_t)bc * 262144;
  const int tid = (int)threadIdx.x, w = tid >> 6, l = tid & 63;
  const int wr = w >> 1, wc = w & 1;
  const size_t row0 = (size_t)blockIdx.x * 128 + (wr << 6) + ((l >> 4) << 2);
  const size_t col0 = (size_t)blockIdx.y * 128 + (wc << 6) + (l & 15);
#pragma unroll
  for (int m = 0; m < 4; ++m)
#pragma unroll
    for (int n = 0; n < 4; ++n)
#pragma unroll
      for (int r = 0; r < 4; ++r)
        Mc[(row0 + (m << 4) + r) * 512 + col0 + (n << 4)] = bfbits(acc[m][n][r]);
}

// ---- y_c = (Q_c St_c^T + G_c Vt_c^T) / den ----
__global__ __launch_bounds__(256) void k_gemm_y(const ushort* __restrict__ q,
                                                const ushort* __restrict__ G,
                                                const ushort* __restrict__ St,
                                                const ushort* __restrict__ Vt,
                                                const float* __restrict__ den,
                                                ushort* __restrict__ Y) {
  __shared__ __align__(16) ushort As[4096], Bs[4096];
  const int trow = blockIdx.x, et = blockIdx.y, bc = blockIdx.z;
  ACC_INIT
  gemm_core(q + (size_t)bc * 131072 + (size_t)trow * 128 * 512, 512,
            St + (size_t)bc * 262144 + (size_t)et * 128 * 512, 512, 16, As, Bs, acc);
  gemm_core(G + (size_t)bc * 65536 + (size_t)trow * 128 * 256, 256,
            Vt + (size_t)et * 128 * 16384 + (size_t)bc * 256, 16384, trow ? 8 : 4, As, Bs, acc);
  const int tid = (int)threadIdx.x, w = tid >> 6, l = tid & 63;
  const int wr = w >> 1, wc = w & 1;
  const int tg0 = bc * 256 + trow * 128 + (wr << 6) + ((l >> 4) << 2);
  const size_t col0 = (size_t)et * 128 + (wc << 6) + (l & 15);
#pragma unroll
  for (int m = 0; m < 4; ++m)
#pragma unroll
    for (int n = 0; n < 4; ++n)
#pragma unroll
      for (int r = 0; r < 4; ++r) {
        int tg = tg0 + (m << 4) + r;
        float v = acc[m][n][r] / den[tg];
        Y[(size_t)tg * 512 + col0 + (n << 4)] = bfbits(v);
      }
}

// ---- small kernels ----
__global__ __launch_bounds__(256) void k_conv_x(const float* __restrict__ x,
                                                ushort* __restrict__ xb) {
  size_t i = ((size_t)blockIdx.x * 256 + threadIdx.x) * 8;
  float4 f0 = *(const float4*)&x[i], f1 = *(const float4*)&x[i + 4];
  ushort8 o;
  o[0] = bfbits(f0.x); o[1] = bfbits(f0.y); o[2] = bfbits(f0.z); o[3] = bfbits(f0.w);
  o[4] = bfbits(f1.x); o[5] = bfbits(f1.y); o[6] = bfbits(f1.z); o[7] = bfbits(f1.w);
  *(ushort8*)&xb[i] = o;
}

__global__ __launch_bounds__(256) void k_wt(const float* __restrict__ Wq,
                                            const float* __restrict__ Wk,
                                            const float* __restrict__ Wv,
                                            const float* __restrict__ Wp,
                                            ushort* __restrict__ wt) {
  __shared__ float tile[64][65];
  const float* src = blockIdx.z == 0 ? Wq : blockIdx.z == 1 ? Wk : blockIdx.z == 2 ? Wv : Wp;
  ushort* dst = wt + (size_t)blockIdx.z * 262144;
  const int d0 = blockIdx.x * 64, n0 = blockIdx.y * 64;
  const int tr = threadIdx.x >> 4, tc = (threadIdx.x & 15) << 2;
#pragma unroll
  for (int it = 0; it < 4; ++it) {
    float4 f = *(const float4*)&src[(size_t)(d0 + it * 16 + tr) * 512 + n0 + tc];
    tile[it * 16 + tr][tc + 0] = f.x;
    tile[it * 16 + tr][tc + 1] = f.y;
    tile[it * 16 + tr][tc + 2] = f.z;
    tile[it * 16 + tr][tc + 3] = f.w;
  }
  __syncthreads();
#pragma unroll
  for (int it = 0; it < 4; ++it) {
    int n = it * 16 + tr;
    ushort4 o;
    o.x = bfbits(tile[tc + 0][n]);
    o.y = bfbits(tile[tc + 1][n]);
    o.z = bfbits(tile[tc + 2][n]);
    o.w = bfbits(tile[tc + 3][n]);
    *(ushort4*)&dst[(size_t)(n0 + n) * 512 + d0 + tc] = o;
  }
}

__global__ __launch_bounds__(256) void k_zsum(const ushort* __restrict__ kk,
                                              float* __restrict__ zp) {
  const int bc = blockIdx.x;
  const ushort* kb = kk + (size_t)bc * 131072;
  const int d0 = threadIdx.x * 2;
  float s0 = 0.f, s1 = 0.f;
  for (int t = 0; t < 256; ++t) {
    unsigned int u = *(const unsigned int*)&kb[(size_t)t * 512 + d0];
    s0 += bff((unsigned short)(u & 0xffffu));
    s1 += bff((unsigned short)(u >> 16));
  }
  zp[(size_t)bc * 512 + d0] = s0;
  zp[(size_t)bc * 512 + d0 + 1] = s1;
}

__global__ __launch_bounds__(256) void k_zscan(float* __restrict__ zp) {
  int gid = blockIdx.x * 256 + threadIdx.x;  // 4096 = 8 b * 512 d
  int b = gid >> 9, d = gid & 511;
  float a = 0.f;
#pragma unroll
  for (int c = 0; c < 8; ++c) {
    size_t idx = (size_t)(b * 8 + c) * 512 + d;
    float t = zp[idx];
    zp[idx] = a;
    a += t;
  }
}

__global__ __launch_bounds__(256) void k_den(const ushort* __restrict__ q,
                                             const ushort* __restrict__ G,
                                             const float* __restrict__ zp,
                                             float* __restrict__ den) {
  const int l = threadIdx.x & 63;
  const int bt = blockIdx.x * 4 + (threadIdx.x >> 6);
  const int b = bt >> 11, t = bt & 2047, c = t >> 8, tl = t & 255;
  const int bc = b * 8 + c;
  const ushort* qrow = q + (size_t)bt * 512;
  const float* zprow = zp + (size_t)bc * 512;
  const int d0 = l * 8;
  ushort8 qv = *(const ushort8*)&qrow[d0];
  float4 z0 = *(const float4*)&zprow[d0], z1 = *(const float4*)&zprow[d0 + 4];
  float s = 0.f;
  s += bff(qv[0]) * z0.x + bff(qv[1]) * z0.y + bff(qv[2]) * z0.z + bff(qv[3]) * z0.w;
  s += bff(qv[4]) * z1.x + bff(qv[5]) * z1.y + bff(qv[6]) * z1.z + bff(qv[7]) * z1.w;
  const ushort* grow = G + (size_t)bc * 65536 + (size_t)tl * 256;
  const int limit = (tl & 128) ? 256 : 128;
  for (int ss = l; ss < limit; ss += 64) s += bff(grow[ss]);
#pragma unroll
  for (int off = 32; off >= 1; off >>= 1) s += __shfl_xor(s, off, 64);
  if (l == 0) den[bt] = s + 1e-6f;
}

__global__ __launch_bounds__(256) void k_prefix(ushort* __restrict__ Mt) {
  const int b = blockIdx.x >> 7, blk = blockIdx.x & 127;
  const size_t p = (size_t)blk * 2048 + (size_t)threadIdx.x * 8;
  float a[8] = {0.f, 0.f, 0.f, 0.f, 0.f, 0.f, 0.f, 0.f};
#pragma unroll
  for (int c = 0; c < 8; ++c) {
    ushort* ptr = Mt + (size_t)(b * 8 + c) * 262144 + p;
    ushort8 mv = *(ushort8*)ptr;
    ushort8 ov;
#pragma unroll
    for (int j = 0; j < 8; ++j) {
      ov[j] = bfbits(a[j]);
      a[j] += bff(mv[j]);
    }
    *(ushort8*)ptr = ov;
  }
}

extern "C" void kernel_launch(void* const* d_in, const int* in_sizes, int n_in,
                              void* d_out, int out_size, void* d_ws, size_t ws_size,
                              hipStream_t stream) {
  const float* x  = (const float*)d_in[0];
  const float* Wq = (const float*)d_in[1];
  const float* Wk = (const float*)d_in[2];
  const float* Wv = (const float*)d_in[3];
  const float* Wp = (const float*)d_in[4];
  float* out = (float*)d_out;
  char* ws8 = (char*)d_ws;
  if (ws_size < WS_NEED) return;

  ushort* xb  = (ushort*)(ws8 + OFF_XB);
  ushort* wt  = (ushort*)(ws8 + OFF_WT);
  ushort* WqT = wt, *WkT = wt + 262144, *WvT = wt + 524288, *WpT = wt + 786432;
  ushort* qb  = (ushort*)(ws8 + OFF_Q);
  ushort* kkb = (ushort*)(ws8 + OFF_KK);
  ushort* Kt  = (ushort*)(ws8 + OFF_KT);
  ushort* Vt  = (ushort*)(ws8 + OFF_VT);
  ushort* G   = (ushort*)(ws8 + OFF_G);
  ushort* Mt  = (ushort*)(ws8 + OFF_MT);
  ushort* Y   = (ushort*)(ws8 + OFF_Y);
  float*  zp  = (float*)(ws8 + OFF_ZP);
  float*  den = (float*)(ws8 + OFF_DEN);

  k_conv_x<<<4096, 256, 0, stream>>>(x, xb);
  k_wt<<<dim3(8, 8, 4), 256, 0, stream>>>(Wq, Wk, Wv, Wp, wt);

  k_gemm<1><<<dim3(128, 4), 256, 0, stream>>>(xb, 512, WqT, 512, qb, 512, 16);
  k_gemm<1><<<dim3(128, 4), 256, 0, stream>>>(xb, 512, WkT, 512, kkb, 512, 16);
  k_gemm<1><<<dim3(4, 128), 256, 0, stream>>>(WkT, 512, xb, 512, Kt, 16384, 16);
  k_gemm<0><<<dim3(4, 128), 256, 0, stream>>>(WvT, 512, xb, 512, Vt, 16384, 16);

  k_zsum<<<64, 256, 0, stream>>>(kkb, zp);
  k_zscan<<<16, 256, 0, stream>>>(zp);

  k_gemm_G<<<dim3(3, 64), 256, 0, stream>>>(qb, kkb, G);
  k_den<<<4096, 256, 0, stream>>>(qb, G, zp, den);

  k_gemm_M<<<dim3(4, 4, 64), 256, 0, stream>>>(Kt, Vt, Mt);
  k_prefix<<<1024, 256, 0, stream>>>(Mt);

  k_gemm_y<<<dim3(2, 4, 64), 256, 0, stream>>>(qb, G, Mt, Vt, den, Y);
  k_gemm<2><<<dim3(128, 4), 256, 0, stream>>>(Y, 512, WpT, 512, out, 512, 16);
}

// Round 3
// 189.840 us; speedup vs baseline: 4.8959x; 1.0977x over previous
//
#include <hip/hip_runtime.h>

// Linear attention (B=8, T=2048, D=512), chunked, bf16 MFMA, fp32 acc.
// R3: 256x256-tile 8-wave 8-phase pipelined GEMM core (T3+T4+T2+T5) for the
// five big GEMM shapes; G on the old 128x128 core; small kernels unchanged.
// All GEMMs are C = A * B^T with A:[M][K], B:[N][K] row-major bf16.

typedef __attribute__((ext_vector_type(4))) float f32x4;
typedef __attribute__((ext_vector_type(8))) __bf16 bf16x8;
typedef __attribute__((ext_vector_type(8))) unsigned short ushort8;

// ---- ws layout (byte offsets) ----
constexpr size_t OFF_XB  = 0;                  // bf16 [16384][512]
constexpr size_t OFF_WT  = OFF_XB + 16777216;  // bf16 4x [512][512] (WqT,WkT,WvT,WpT)
constexpr size_t OFF_Q   = OFF_WT + 2097152;   // bf16 [16384][512]
constexpr size_t OFF_KK  = OFF_Q  + 16777216;  // bf16 [16384][512]
constexpr size_t OFF_KT  = OFF_KK + 16777216;  // bf16 [512][16384]
constexpr size_t OFF_VT  = OFF_KT + 16777216;  // bf16 [512][16384]
constexpr size_t OFF_G   = OFF_VT + 16777216;  // bf16 [64][256][256]
constexpr size_t OFF_MT  = OFF_G  + 8388608;   // bf16 [64][512][512] (becomes St)
constexpr size_t OFF_Y   = OFF_MT + 33554432;  // bf16 [16384][512]
constexpr size_t OFF_ZP  = OFF_Y  + 16777216;  // f32  [64][512]
constexpr size_t OFF_DEN = OFF_ZP + 131072;    // f32  [16384]
constexpr size_t WS_NEED = OFF_DEN + 65536;

__device__ __forceinline__ unsigned short bfbits(float f) {
  __bf16 h = (__bf16)f;
  return __builtin_bit_cast(unsigned short, h);
}
__device__ __forceinline__ float bff(unsigned short u) {
  return (float)__builtin_bit_cast(__bf16, u);
}

__device__ __forceinline__ void gload16(const void* g, void* l) {
  __builtin_amdgcn_global_load_lds((const __attribute__((address_space(1))) void*)g,
                                   (__attribute__((address_space(3))) void*)l, 16, 0, 0);
}

// ======================= 256x256 8-wave 8-phase core =======================
// LDS: A[2 buf][2 half][128 rows][64 cols] bf16 + same for B = 128 KiB.
// Half-tile = 16 KiB, staged by 2 global_load_lds rounds (8 KiB each).
// Swizzle (involution, both sides): byte ^= ((row & 7) << 4).

__device__ __forceinline__ void stage_half(const char* gRow0, size_t ld2, int k0b,
                                           char* ldsHalf, int w, int lane) {
#pragma unroll
  for (int i = 0; i < 2; ++i) {
    int L = (w << 10) + (lane << 4) + (i << 13);
    int r = L >> 7;
    int cb = (L & 127) ^ ((r & 7) << 4);
    gload16(gRow0 + (size_t)r * ld2 + k0b + cb, ldsHalf + (w << 10) + (i << 13));
  }
}

__device__ __forceinline__ const bf16x8* frag_at(const char* halfBase, int rowInHalf,
                                                 int colByte) {
  int lin = (rowInHalf << 7) + colByte;
  lin ^= (rowInHalf & 7) << 4;
  return (const bf16x8*)(halfBase + lin);
}

#define QUAD(mh, nh)                                                                   \
  _Pragma("unroll") for (int mm = 0; mm < 4; ++mm)                                     \
  _Pragma("unroll") for (int nn = 0; nn < 2; ++nn)                                     \
  _Pragma("unroll") for (int s = 0; s < 2; ++s)                                        \
      acc[(mh)*4 + mm][(nh)*2 + nn] = __builtin_amdgcn_mfma_f32_16x16x32_bf16(         \
          af[(mh)*4 + mm][s], bg[(nh)*2 + nn][s], acc[(mh)*4 + mm][(nh)*2 + nn], 0, 0, 0);

#define PHASE_TAIL(MH, NH)                                       \
  __builtin_amdgcn_s_barrier();                                  \
  asm volatile("s_waitcnt lgkmcnt(0)" ::: "memory");             \
  __builtin_amdgcn_sched_barrier(0);                             \
  __builtin_amdgcn_s_setprio(1);                                 \
  QUAD(MH, NH);                                                  \
  __builtin_amdgcn_s_setprio(0);                                 \
  __builtin_amdgcn_s_barrier();

// A,B byte pointers at (tile_row0, k=0); strides in bytes; nt = K/64 (>=2).
__device__ __forceinline__ void core8(const char* Ab, size_t lda2, const char* Bb,
                                      size_t ldb2, int nt, char* sA, char* sB,
                                      f32x4 (&acc)[8][4], int w, int lane) {
  const int mr = w >> 2, nc = w & 3;
  const int fr = lane & 15, foB = (lane >> 4) << 4;
  const int brow = (nc & 1) << 6;
  const char* gA0 = Ab;
  const char* gA1 = Ab + (size_t)128 * lda2;
  const char* gB0 = Bb;
  const char* gB1 = Bb + (size_t)128 * ldb2;
  bf16x8 af[8][2], bg[4][2];

  // prologue: tile0 A+B, tile1 A
  stage_half(gA0, lda2, 0, sA + 0 * 16384, w, lane);
  stage_half(gA1, lda2, 0, sA + 1 * 16384, w, lane);
  stage_half(gB0, ldb2, 0, sB + 0 * 16384, w, lane);
  stage_half(gB1, ldb2, 0, sB + 1 * 16384, w, lane);
  if (nt > 1) {
    stage_half(gA0, lda2, 128, sA + 2 * 16384, w, lane);
    stage_half(gA1, lda2, 128, sA + 3 * 16384, w, lane);
    asm volatile("s_waitcnt vmcnt(4)" ::: "memory");
  } else {
    asm volatile("s_waitcnt vmcnt(0)" ::: "memory");
  }
  __builtin_amdgcn_sched_barrier(0);
  __builtin_amdgcn_s_barrier();

  for (int t = 0; t < nt; ++t) {
    const int buf = t & 1;
    const char* cA = sA + buf * 32768 + mr * 16384;
    const char* cB = sB + buf * 32768 + (nc >> 1) * 16384;
    char* nA = sA + buf * 32768;            // tile t+2 shares this buffer
    char* nB = sB + (buf ^ 1) * 32768;      // tile t+1
    const int kb1 = (t + 1) << 7, kb2 = (t + 2) << 7;
    const bool stB = (t + 1 < nt), stA = (t + 2 < nt);

    // ---- p0: quadrant (0,0); reads af[0-3], bg[0-1]; stages B-h0(t+1)
#pragma unroll
    for (int m = 0; m < 4; ++m)
#pragma unroll
      for (int s = 0; s < 2; ++s) af[m][s] = *frag_at(cA, m * 16 + fr, s * 64 + foB);
#pragma unroll
    for (int n = 0; n < 2; ++n)
#pragma unroll
      for (int s = 0; s < 2; ++s)
        bg[n][s] = *frag_at(cB, brow + n * 16 + fr, s * 64 + foB);
    if (stB) stage_half(gB0, ldb2, kb1, nB + 0 * 16384, w, lane);
    PHASE_TAIL(0, 0)

    // ---- p1: quadrant (1,0); reads af[4-7]; stages B-h1(t+1)
#pragma unroll
    for (int m = 4; m < 8; ++m)
#pragma unroll
      for (int s = 0; s < 2; ++s) af[m][s] = *frag_at(cA, m * 16 + fr, s * 64 + foB);
    if (stB) stage_half(gB1, ldb2, kb1, nB + 1 * 16384, w, lane);
    PHASE_TAIL(1, 0)

    // ---- p2: quadrant (0,1); reads bg[2-3]; stages A-h0(t+2)
#pragma unroll
    for (int n = 2; n < 4; ++n)
#pragma unroll
      for (int s = 0; s < 2; ++s)
        bg[n][s] = *frag_at(cB, brow + n * 16 + fr, s * 64 + foB);
    if (stA) stage_half(gA0, lda2, kb2, nA + 0 * 16384, w, lane);
    PHASE_TAIL(0, 1)

    // ---- p3: quadrant (1,1); stages A-h1(t+2); per-tile counted vmcnt
    if (stA) stage_half(gA1, lda2, kb2, nA + 1 * 16384, w, lane);
    if (t < nt - 2) {
      asm volatile("s_waitcnt vmcnt(4)" ::: "memory");
      __builtin_amdgcn_sched_barrier(0);
    } else if (t == nt - 2) {
      asm volatile("s_waitcnt vmcnt(0)" ::: "memory");
      __builtin_amdgcn_sched_barrier(0);
    }
    PHASE_TAIL(1, 1)
  }
}

#define ACC8_INIT                                    \
  f32x4 acc[8][4];                                   \
  _Pragma("unroll") for (int m_ = 0; m_ < 8; ++m_)   \
  _Pragma("unroll") for (int n_ = 0; n_ < 4; ++n_)   \
      acc[m_][n_] = f32x4{0.f, 0.f, 0.f, 0.f};

// ---- q = phi(xb WqT^T), kk = phi(xb WkT^T); z selects ----
__global__ __launch_bounds__(512, 2) void k8_proj(const ushort* __restrict__ xb,
                                                  const ushort* __restrict__ wt,
                                                  ushort* __restrict__ qb,
                                                  ushort* __restrict__ kkb) {
  extern __shared__ char smem[];
  const int tid = threadIdx.x, w = tid >> 6, lane = tid & 63;
  const ushort* A = xb + (size_t)blockIdx.x * 256 * 512;
  const ushort* B = wt + (size_t)blockIdx.z * 262144 + (size_t)blockIdx.y * 256 * 512;
  ushort* C = blockIdx.z == 0 ? qb : kkb;
  ACC8_INIT
  core8((const char*)A, 1024, (const char*)B, 1024, 8, smem, smem + 65536, acc, w, lane);
  const int mr = w >> 2, nc = w & 3, fr = lane & 15, q4 = (lane >> 4) << 2;
  const size_t row0 = (size_t)blockIdx.x * 256 + mr * 128;
  const size_t col0 = (size_t)blockIdx.y * 256 + nc * 64;
#pragma unroll
  for (int m = 0; m < 8; ++m)
#pragma unroll
    for (int n = 0; n < 4; ++n)
#pragma unroll
      for (int r = 0; r < 4; ++r) {
        float v = acc[m][n][r];
        v = v > 0.f ? v + 1.f : __expf(v);
        C[(row0 + m * 16 + q4 + r) * 512 + col0 + n * 16 + fr] = bfbits(v);
      }
}

// ---- Kt = phi(WkT xb^T) (z=0), Vt = WvT xb^T (z=1) ----
__global__ __launch_bounds__(512, 2) void k8_projT(const ushort* __restrict__ xb,
                                                   const ushort* __restrict__ wt,
                                                   ushort* __restrict__ Kt,
                                                   ushort* __restrict__ Vt) {
  extern __shared__ char smem[];
  const int tid = threadIdx.x, w = tid >> 6, lane = tid & 63;
  const int z = blockIdx.z;
  const ushort* A = wt + (z == 0 ? 262144 : 524288) + (size_t)blockIdx.x * 256 * 512;
  const ushort* B = xb + (size_t)blockIdx.y * 256 * 512;
  ushort* C = z == 0 ? Kt : Vt;
  ACC8_INIT
  core8((const char*)A, 1024, (const char*)B, 1024, 8, smem, smem + 65536, acc, w, lane);
  const int mr = w >> 2, nc = w & 3, fr = lane & 15, q4 = (lane >> 4) << 2;
  const size_t row0 = (size_t)blockIdx.x * 256 + mr * 128;
  const size_t col0 = (size_t)blockIdx.y * 256 + nc * 64;
#pragma unroll
  for (int m = 0; m < 8; ++m)
#pragma unroll
    for (int n = 0; n < 4; ++n)
#pragma unroll
      for (int r = 0; r < 4; ++r) {
        float v = acc[m][n][r];
        if (z == 0) v = v > 0.f ? v + 1.f : __expf(v);
        C[(row0 + m * 16 + q4 + r) * 16384 + col0 + n * 16 + fr] = bfbits(v);
      }
}

// ---- Mt_c = Vt_c Kt_c^T ----
__global__ __launch_bounds__(512, 2) void k8_M(const ushort* __restrict__ Kt,
                                               const ushort* __restrict__ Vt,
                                               ushort* __restrict__ Mt) {
  extern __shared__ char smem[];
  const int tid = threadIdx.x, w = tid >> 6, lane = tid & 63;
  const int bc = blockIdx.z;
  const ushort* A = Vt + (size_t)bc * 256 + (size_t)blockIdx.x * 256 * 16384;
  const ushort* B = Kt + (size_t)bc * 256 + (size_t)blockIdx.y * 256 * 16384;
  ACC8_INIT
  core8((const char*)A, 32768, (const char*)B, 32768, 4, smem, smem + 65536, acc, w, lane);
  ushort* C = Mt + (size_t)bc * 262144;
  const int mr = w >> 2, nc = w & 3, fr = lane & 15, q4 = (lane >> 4) << 2;
  const size_t row0 = (size_t)blockIdx.x * 256 + mr * 128;
  const size_t col0 = (size_t)blockIdx.y * 256 + nc * 64;
#pragma unroll
  for (int m = 0; m < 8; ++m)
#pragma unroll
    for (int n = 0; n < 4; ++n)
#pragma unroll
      for (int r = 0; r < 4; ++r)
        C[(row0 + m * 16 + q4 + r) * 512 + col0 + n * 16 + fr] = bfbits(acc[m][n][r]);
}

// ---- y_c = (Q_c St_c^T + G_c Vt_c^T) / den ----
__global__ __launch_bounds__(512, 2) void k8_y(const ushort* __restrict__ qb,
                                               const ushort* __restrict__ G,
                                               const ushort* __restrict__ Mt,
                                               const ushort* __restrict__ Vt,
                                               const float* __restrict__ den,
                                               ushort* __restrict__ Y) {
  extern __shared__ char smem[];
  const int tid = threadIdx.x, w = tid >> 6, lane = tid & 63;
  const int by = blockIdx.x, bc = blockIdx.y;
  ACC8_INIT
  core8((const char*)(qb + (size_t)bc * 131072), 1024,
        (const char*)(Mt + (size_t)bc * 262144 + (size_t)by * 256 * 512), 1024, 8,
        smem, smem + 65536, acc, w, lane);
  core8((const char*)(G + (size_t)bc * 65536), 512,
        (const char*)(Vt + (size_t)bc * 256 + (size_t)by * 256 * 16384), 32768, 4,
        smem, smem + 65536, acc, w, lane);
  const int mr = w >> 2, nc = w & 3, fr = lane & 15, q4 = (lane >> 4) << 2;
  const size_t row0 = (size_t)bc * 256 + mr * 128;
  const size_t col0 = (size_t)by * 256 + nc * 64;
#pragma unroll
  for (int m = 0; m < 8; ++m)
#pragma unroll
    for (int n = 0; n < 4; ++n)
#pragma unroll
      for (int r = 0; r < 4; ++r) {
        size_t row = row0 + m * 16 + q4 + r;
        float v = acc[m][n][r] / den[row];
        Y[row * 512 + col0 + n * 16 + fr] = bfbits(v);
      }
}

// ---- out = Y WpT^T (fp32 store) ----
__global__ __launch_bounds__(512, 2) void k8_out(const ushort* __restrict__ Y,
                                                 const ushort* __restrict__ wt,
                                                 float* __restrict__ out) {
  extern __shared__ char smem[];
  const int tid = threadIdx.x, w = tid >> 6, lane = tid & 63;
  const ushort* A = Y + (size_t)blockIdx.x * 256 * 512;
  const ushort* B = wt + 786432 + (size_t)blockIdx.y * 256 * 512;
  ACC8_INIT
  core8((const char*)A, 1024, (const char*)B, 1024, 8, smem, smem + 65536, acc, w, lane);
  const int mr = w >> 2, nc = w & 3, fr = lane & 15, q4 = (lane >> 4) << 2;
  const size_t row0 = (size_t)blockIdx.x * 256 + mr * 128;
  const size_t col0 = (size_t)blockIdx.y * 256 + nc * 64;
#pragma unroll
  for (int m = 0; m < 8; ++m)
#pragma unroll
    for (int n = 0; n < 4; ++n)
#pragma unroll
      for (int r = 0; r < 4; ++r)
        out[(row0 + m * 16 + q4 + r) * 512 + col0 + n * 16 + fr] = acc[m][n][r];
}

// ======================= old 128x128 core (G only) =======================
__device__ __forceinline__ void gemm_core(const ushort* __restrict__ A, int lda,
                                          const ushort* __restrict__ B, int ldb,
                                          int ksteps, ushort* As, ushort* Bs,
                                          f32x4 acc[4][4]) {
  const int tid = (int)threadIdx.x;
  const int w = tid >> 6, l = tid & 63;
  const int wr = w >> 1, wc = w & 1;
  const int srow = (w << 5) + (l >> 2);
  const int scol = (l & 3) << 3;
  const ushort* ga = A + (size_t)srow * lda + scol;
  const ushort* gb = B + (size_t)srow * ldb + scol;
  ushort* lA0 = As + (w << 10);
  ushort* lA1 = As + (w << 10) + 512;
  ushort* lB0 = Bs + (w << 10);
  ushort* lB1 = Bs + (w << 10) + 512;
  const int fr = l & 15, fk = (l >> 4) << 3;
  for (int s = 0; s < ksteps; ++s) {
    __syncthreads();
    const ushort* gao = ga + s * 32;
    const ushort* gbo = gb + s * 32;
    gload16(gao, lA0);
    gload16(gao + (size_t)16 * lda, lA1);
    gload16(gbo, lB0);
    gload16(gbo + (size_t)16 * ldb, lB1);
    __syncthreads();
    bf16x8 af[4], bg[4];
#pragma unroll
    for (int m = 0; m < 4; ++m)
      af[m] = *(const bf16x8*)&As[(((wr << 6) + (m << 4) + fr) << 5) + fk];
#pragma unroll
    for (int n = 0; n < 4; ++n)
      bg[n] = *(const bf16x8*)&Bs[(((wc << 6) + (n << 4) + fr) << 5) + fk];
#pragma unroll
    for (int m = 0; m < 4; ++m)
#pragma unroll
      for (int n = 0; n < 4; ++n)
        acc[m][n] = __builtin_amdgcn_mfma_f32_16x16x32_bf16(af[m], bg[n], acc[m][n], 0, 0, 0);
  }
}

// ---- G = tril(Q_c K_c^T): tiles 0:(0,0) 1:(1,0) 2:(1,1) ----
__global__ __launch_bounds__(256) void k_gemm_G(const ushort* __restrict__ q,
                                                const ushort* __restrict__ kk,
                                                ushort* __restrict__ G) {
  __shared__ __align__(16) ushort As[4096], Bs[4096];
  const int tile = blockIdx.x;
  const int ti = (tile == 0) ? 0 : 1, tj = (tile == 2) ? 1 : 0;
  const int bc = blockIdx.y;
  f32x4 acc[4][4];
#pragma unroll
  for (int m_ = 0; m_ < 4; ++m_)
#pragma unroll
    for (int n_ = 0; n_ < 4; ++n_) acc[m_][n_] = f32x4{0.f, 0.f, 0.f, 0.f};
  gemm_core(q + (size_t)bc * 131072 + (size_t)ti * 128 * 512, 512,
            kk + (size_t)bc * 131072 + (size_t)tj * 128 * 512, 512, 16, As, Bs, acc);
  ushort* Gc = G + (size_t)bc * 65536;
  const int tid = (int)threadIdx.x, w = tid >> 6, l = tid & 63;
  const int wr = w >> 1, wc = w & 1;
  const int rbase = ti * 128 + (wr << 6) + ((l >> 4) << 2);
  const int cbase = tj * 128 + (wc << 6) + (l & 15);
#pragma unroll
  for (int i = 0; i < 4; ++i)
#pragma unroll
    for (int n = 0; n < 4; ++n)
#pragma unroll
      for (int r = 0; r < 4; ++r) {
        int row = rbase + (i << 4) + r, col = cbase + (n << 4);
        float v = (col <= row) ? acc[i][n][r] : 0.f;
        Gc[(size_t)row * 256 + col] = bfbits(v);
      }
}

// ======================= small kernels =======================
__global__ __launch_bounds__(256) void k_conv_x(const float* __restrict__ x,
                                                ushort* __restrict__ xb) {
  size_t i = ((size_t)blockIdx.x * 256 + threadIdx.x) * 8;
  float4 f0 = *(const float4*)&x[i], f1 = *(const float4*)&x[i + 4];
  ushort8 o;
  o[0] = bfbits(f0.x); o[1] = bfbits(f0.y); o[2] = bfbits(f0.z); o[3] = bfbits(f0.w);
  o[4] = bfbits(f1.x); o[5] = bfbits(f1.y); o[6] = bfbits(f1.z); o[7] = bfbits(f1.w);
  *(ushort8*)&xb[i] = o;
}

__global__ __launch_bounds__(256) void k_wt(const float* __restrict__ Wq,
                                            const float* __restrict__ Wk,
                                            const float* __restrict__ Wv,
                                            const float* __restrict__ Wp,
                                            ushort* __restrict__ wt) {
  __shared__ float tile[64][65];
  const float* src = blockIdx.z == 0 ? Wq : blockIdx.z == 1 ? Wk : blockIdx.z == 2 ? Wv : Wp;
  ushort* dst = wt + (size_t)blockIdx.z * 262144;
  const int d0 = blockIdx.x * 64, n0 = blockIdx.y * 64;
  const int tr = threadIdx.x >> 4, tc = (threadIdx.x & 15) << 2;
#pragma unroll
  for (int it = 0; it < 4; ++it) {
    float4 f = *(const float4*)&src[(size_t)(d0 + it * 16 + tr) * 512 + n0 + tc];
    tile[it * 16 + tr][tc + 0] = f.x;
    tile[it * 16 + tr][tc + 1] = f.y;
    tile[it * 16 + tr][tc + 2] = f.z;
    tile[it * 16 + tr][tc + 3] = f.w;
  }
  __syncthreads();
#pragma unroll
  for (int it = 0; it < 4; ++it) {
    int n = it * 16 + tr;
    ushort4 o;
    o.x = bfbits(tile[tc + 0][n]);
    o.y = bfbits(tile[tc + 1][n]);
    o.z = bfbits(tile[tc + 2][n]);
    o.w = bfbits(tile[tc + 3][n]);
    *(ushort4*)&dst[(size_t)(n0 + n) * 512 + d0 + tc] = o;
  }
}

__global__ __launch_bounds__(256) void k_zsum(const ushort* __restrict__ kk,
                                              float* __restrict__ zp) {
  const int bc = blockIdx.x;
  const ushort* kb = kk + (size_t)bc * 131072;
  const int d0 = threadIdx.x * 2;
  float s0 = 0.f, s1 = 0.f;
  for (int t = 0; t < 256; ++t) {
    unsigned int u = *(const unsigned int*)&kb[(size_t)t * 512 + d0];
    s0 += bff((unsigned short)(u & 0xffffu));
    s1 += bff((unsigned short)(u >> 16));
  }
  zp[(size_t)bc * 512 + d0] = s0;
  zp[(size_t)bc * 512 + d0 + 1] = s1;
}

__global__ __launch_bounds__(256) void k_zscan(float* __restrict__ zp) {
  int gid = blockIdx.x * 256 + threadIdx.x;
  int b = gid >> 9, d = gid & 511;
  float a = 0.f;
#pragma unroll
  for (int c = 0; c < 8; ++c) {
    size_t idx = (size_t)(b * 8 + c) * 512 + d;
    float t = zp[idx];
    zp[idx] = a;
    a += t;
  }
}

__global__ __launch_bounds__(256) void k_den(const ushort* __restrict__ q,
                                             const ushort* __restrict__ G,
                                             const float* __restrict__ zp,
                                             float* __restrict__ den) {
  const int l = threadIdx.x & 63;
  const int bt = blockIdx.x * 4 + (threadIdx.x >> 6);
  const int b = bt >> 11, t = bt & 2047, c = t >> 8, tl = t & 255;
  const int bc = b * 8 + c;
  const ushort* qrow = q + (size_t)bt * 512;
  const float* zprow = zp + (size_t)bc * 512;
  const int d0 = l * 8;
  ushort8 qv = *(const ushort8*)&qrow[d0];
  float4 z0 = *(const float4*)&zprow[d0], z1 = *(const float4*)&zprow[d0 + 4];
  float s = 0.f;
  s += bff(qv[0]) * z0.x + bff(qv[1]) * z0.y + bff(qv[2]) * z0.z + bff(qv[3]) * z0.w;
  s += bff(qv[4]) * z1.x + bff(qv[5]) * z1.y + bff(qv[6]) * z1.z + bff(qv[7]) * z1.w;
  const ushort* grow = G + (size_t)bc * 65536 + (size_t)tl * 256;
  const int limit = (tl & 128) ? 256 : 128;
  for (int ss = l; ss < limit; ss += 64) s += bff(grow[ss]);
#pragma unroll
  for (int off = 32; off >= 1; off >>= 1) s += __shfl_xor(s, off, 64);
  if (l == 0) den[bt] = s + 1e-6f;
}

__global__ __launch_bounds__(256) void k_prefix(ushort* __restrict__ Mt) {
  const int b = blockIdx.x >> 7, blk = blockIdx.x & 127;
  const size_t p = (size_t)blk * 2048 + (size_t)threadIdx.x * 8;
  float a[8] = {0.f, 0.f, 0.f, 0.f, 0.f, 0.f, 0.f, 0.f};
#pragma unroll
  for (int c = 0; c < 8; ++c) {
    ushort* ptr = Mt + (size_t)(b * 8 + c) * 262144 + p;
    ushort8 mv = *(ushort8*)ptr;
    ushort8 ov;
#pragma unroll
    for (int j = 0; j < 8; ++j) {
      ov[j] = bfbits(a[j]);
      a[j] += bff(mv[j]);
    }
    *(ushort8*)ptr = ov;
  }
}

extern "C" void kernel_launch(void* const* d_in, const int* in_sizes, int n_in,
                              void* d_out, int out_size, void* d_ws, size_t ws_size,
                              hipStream_t stream) {
  const float* x  = (const float*)d_in[0];
  const float* Wq = (const float*)d_in[1];
  const float* Wk = (const float*)d_in[2];
  const float* Wv = (const float*)d_in[3];
  const float* Wp = (const float*)d_in[4];
  float* out = (float*)d_out;
  char* ws8 = (char*)d_ws;
  if (ws_size < WS_NEED) return;

  ushort* xb  = (ushort*)(ws8 + OFF_XB);
  ushort* wt  = (ushort*)(ws8 + OFF_WT);
  ushort* qb  = (ushort*)(ws8 + OFF_Q);
  ushort* kkb = (ushort*)(ws8 + OFF_KK);
  ushort* Kt  = (ushort*)(ws8 + OFF_KT);
  ushort* Vt  = (ushort*)(ws8 + OFF_VT);
  ushort* G   = (ushort*)(ws8 + OFF_G);
  ushort* Mt  = (ushort*)(ws8 + OFF_MT);
  ushort* Y   = (ushort*)(ws8 + OFF_Y);
  float*  zp  = (float*)(ws8 + OFF_ZP);
  float*  den = (float*)(ws8 + OFF_DEN);

  constexpr int SMEM = 131072;
  static bool attr_done = false;
  hipFuncSetAttribute((const void*)k8_proj,  hipFuncAttributeMaxDynamicSharedMemorySize, SMEM);
  hipFuncSetAttribute((const void*)k8_projT, hipFuncAttributeMaxDynamicSharedMemorySize, SMEM);
  hipFuncSetAttribute((const void*)k8_M,     hipFuncAttributeMaxDynamicSharedMemorySize, SMEM);
  hipFuncSetAttribute((const void*)k8_y,     hipFuncAttributeMaxDynamicSharedMemorySize, SMEM);
  hipFuncSetAttribute((const void*)k8_out,   hipFuncAttributeMaxDynamicSharedMemorySize, SMEM);
  (void)attr_done;

  // zero G so the never-written strictly-upper tile reads as 0 in k8_y
  hipMemsetAsync(G, 0, 8388608, stream);

  k_conv_x<<<4096, 256, 0, stream>>>(x, xb);
  k_wt<<<dim3(8, 8, 4), 256, 0, stream>>>(Wq, Wk, Wv, Wp, wt);

  k8_proj <<<dim3(64, 2, 2), 512, SMEM, stream>>>(xb, wt, qb, kkb);
  k8_projT<<<dim3(2, 64, 2), 512, SMEM, stream>>>(xb, wt, Kt, Vt);

  k_zsum<<<64, 256, 0, stream>>>(kkb, zp);
  k_zscan<<<16, 256, 0, stream>>>(zp);

  k_gemm_G<<<dim3(3, 64), 256, 0, stream>>>(qb, kkb, G);
  k_den<<<4096, 256, 0, stream>>>(qb, G, zp, den);

  k8_M<<<dim3(2, 2, 64), 512, SMEM, stream>>>(Kt, Vt, Mt);
  k_prefix<<<1024, 256, 0, stream>>>(Mt);

  k8_y<<<dim3(2, 64), 512, SMEM, stream>>>(qb, G, Mt, Vt, den, Y);
  k8_out<<<dim3(64, 2), 512, SMEM, stream>>>(Y, wt, out);
}

// Round 4
// 155.598 us; speedup vs baseline: 5.9733x; 1.2201x over previous
//
#include <hip/hip_runtime.h>

// Linear attention (B=8, T=2048, D=512), chunked, bf16 MFMA, fp32 acc.
// R4: six launches total.
//   k_pre    : bf16(x) + W^T transposes                      (4352 blocks)
//   k8_qkvt  : q, kk (+column-sums zsum), Kt, Vt             (512 blocks, 256-core)
//   k8_MG    : Mt = Vt_c Kt_c^T  and  G = tril(Q_c K_c^T)    (384 blocks, mixed cores)
//   k_dp     : den (q.zpre + rowsum G) and chunk-prefix(Mt)  (5120 blocks)
//   k8_y     : y = (Q St^T + G Vt^T)/den                     (256 blocks, 128-core)
//   k8_out   : out = y Wp^T (fp32)                           (256 blocks, 128-core)
// All GEMMs are C = A * B^T with A:[M][K], B:[N][K] row-major bf16.

typedef __attribute__((ext_vector_type(4))) float f32x4;
typedef __attribute__((ext_vector_type(8))) __bf16 bf16x8;
typedef __attribute__((ext_vector_type(8))) unsigned short ushort8;

// ---- ws layout (byte offsets) ----
constexpr size_t OFF_XB  = 0;                  // bf16 [16384][512]
constexpr size_t OFF_WT  = OFF_XB + 16777216;  // bf16 4x [512][512] (WqT,WkT,WvT,WpT)
constexpr size_t OFF_Q   = OFF_WT + 2097152;   // bf16 [16384][512]
constexpr size_t OFF_KK  = OFF_Q  + 16777216;  // bf16 [16384][512]
constexpr size_t OFF_KT  = OFF_KK + 16777216;  // bf16 [512][16384]
constexpr size_t OFF_VT  = OFF_KT + 16777216;  // bf16 [512][16384]
constexpr size_t OFF_G   = OFF_VT + 16777216;  // bf16 [64][256][256]
constexpr size_t OFF_MT  = OFF_G  + 8388608;   // bf16 [64][512][512] (becomes St)
constexpr size_t OFF_Y   = OFF_MT + 33554432;  // bf16 [16384][512]
constexpr size_t OFF_ZP  = OFF_Y  + 16777216;  // f32  [64][512] per-chunk col sums of kk
constexpr size_t OFF_DEN = OFF_ZP + 131072;    // f32  [16384]
constexpr size_t WS_NEED = OFF_DEN + 65536;

__device__ __forceinline__ unsigned short bfbits(float f) {
  __bf16 h = (__bf16)f;
  return __builtin_bit_cast(unsigned short, h);
}
__device__ __forceinline__ float bff(unsigned short u) {
  return (float)__builtin_bit_cast(__bf16, u);
}

__device__ __forceinline__ void gload16(const void* g, void* l) {
  __builtin_amdgcn_global_load_lds((const __attribute__((address_space(1))) void*)g,
                                   (__attribute__((address_space(3))) void*)l, 16, 0, 0);
}

// Stage one 128-row x 64-col bf16 half-tile (16 KiB) with 512 threads.
// LDS dest is linear; global source is pre-swizzled with the involution
// byte ^= ((row & 7) << 4), matching frag_at's read-side swizzle.
__device__ __forceinline__ void stage_half(const char* gRow0, size_t ld2, int k0b,
                                           char* ldsHalf, int w, int lane) {
#pragma unroll
  for (int i = 0; i < 2; ++i) {
    int L = (w << 10) + (lane << 4) + (i << 13);
    int r = L >> 7;
    int cb = (L & 127) ^ ((r & 7) << 4);
    gload16(gRow0 + (size_t)r * ld2 + k0b + cb, ldsHalf + (w << 10) + (i << 13));
  }
}

__device__ __forceinline__ const bf16x8* frag_at(const char* halfBase, int rowInHalf,
                                                 int colByte) {
  int lin = (rowInHalf << 7) + colByte;
  lin ^= (rowInHalf & 7) << 4;
  return (const bf16x8*)(halfBase + lin);
}

// ======================= 256x256 8-wave 8-phase core =======================
#define QUAD(mh, nh)                                                                   \
  _Pragma("unroll") for (int mm = 0; mm < 4; ++mm)                                     \
  _Pragma("unroll") for (int nn = 0; nn < 2; ++nn)                                     \
  _Pragma("unroll") for (int s = 0; s < 2; ++s)                                        \
      acc[(mh)*4 + mm][(nh)*2 + nn] = __builtin_amdgcn_mfma_f32_16x16x32_bf16(         \
          af[(mh)*4 + mm][s], bg[(nh)*2 + nn][s], acc[(mh)*4 + mm][(nh)*2 + nn], 0, 0, 0);

#define PHASE_TAIL(MH, NH)                                       \
  __builtin_amdgcn_s_barrier();                                  \
  asm volatile("s_waitcnt lgkmcnt(0)" ::: "memory");             \
  __builtin_amdgcn_sched_barrier(0);                             \
  __builtin_amdgcn_s_setprio(1);                                 \
  QUAD(MH, NH);                                                  \
  __builtin_amdgcn_s_setprio(0);                                 \
  __builtin_amdgcn_s_barrier();

__device__ __forceinline__ void core8(const char* Ab, size_t lda2, const char* Bb,
                                      size_t ldb2, int nt, char* sA, char* sB,
                                      f32x4 (&acc)[8][4], int w, int lane) {
  const int mr = w >> 2, nc = w & 3;
  const int fr = lane & 15, foB = (lane >> 4) << 4;
  const int brow = (nc & 1) << 6;
  const char* gA0 = Ab;
  const char* gA1 = Ab + (size_t)128 * lda2;
  const char* gB0 = Bb;
  const char* gB1 = Bb + (size_t)128 * ldb2;
  bf16x8 af[8][2], bg[4][2];

  stage_half(gA0, lda2, 0, sA + 0 * 16384, w, lane);
  stage_half(gA1, lda2, 0, sA + 1 * 16384, w, lane);
  stage_half(gB0, ldb2, 0, sB + 0 * 16384, w, lane);
  stage_half(gB1, ldb2, 0, sB + 1 * 16384, w, lane);
  if (nt > 1) {
    stage_half(gA0, lda2, 128, sA + 2 * 16384, w, lane);
    stage_half(gA1, lda2, 128, sA + 3 * 16384, w, lane);
    asm volatile("s_waitcnt vmcnt(4)" ::: "memory");
  } else {
    asm volatile("s_waitcnt vmcnt(0)" ::: "memory");
  }
  __builtin_amdgcn_sched_barrier(0);
  __builtin_amdgcn_s_barrier();

  for (int t = 0; t < nt; ++t) {
    const int buf = t & 1;
    const char* cA = sA + buf * 32768 + mr * 16384;
    const char* cB = sB + buf * 32768 + (nc >> 1) * 16384;
    char* nA = sA + buf * 32768;
    char* nB = sB + (buf ^ 1) * 32768;
    const int kb1 = (t + 1) << 7, kb2 = (t + 2) << 7;
    const bool stB = (t + 1 < nt), stA = (t + 2 < nt);

#pragma unroll
    for (int m = 0; m < 4; ++m)
#pragma unroll
      for (int s = 0; s < 2; ++s) af[m][s] = *frag_at(cA, m * 16 + fr, s * 64 + foB);
#pragma unroll
    for (int n = 0; n < 2; ++n)
#pragma unroll
      for (int s = 0; s < 2; ++s)
        bg[n][s] = *frag_at(cB, brow + n * 16 + fr, s * 64 + foB);
    if (stB) stage_half(gB0, ldb2, kb1, nB + 0 * 16384, w, lane);
    PHASE_TAIL(0, 0)

#pragma unroll
    for (int m = 4; m < 8; ++m)
#pragma unroll
      for (int s = 0; s < 2; ++s) af[m][s] = *frag_at(cA, m * 16 + fr, s * 64 + foB);
    if (stB) stage_half(gB1, ldb2, kb1, nB + 1 * 16384, w, lane);
    PHASE_TAIL(1, 0)

#pragma unroll
    for (int n = 2; n < 4; ++n)
#pragma unroll
      for (int s = 0; s < 2; ++s)
        bg[n][s] = *frag_at(cB, brow + n * 16 + fr, s * 64 + foB);
    if (stA) stage_half(gA0, lda2, kb2, nA + 0 * 16384, w, lane);
    PHASE_TAIL(0, 1)

    if (stA) stage_half(gA1, lda2, kb2, nA + 1 * 16384, w, lane);
    if (t < nt - 2) {
      asm volatile("s_waitcnt vmcnt(4)" ::: "memory");
      __builtin_amdgcn_sched_barrier(0);
    } else if (t == nt - 2) {
      asm volatile("s_waitcnt vmcnt(0)" ::: "memory");
      __builtin_amdgcn_sched_barrier(0);
    }
    PHASE_TAIL(1, 1)
  }
}

// ======================= 128x256 8-wave 4-phase core =======================
// 8 waves: wr = w>>2 in {0,1}, wc = w&3. Per wave 64x64 = 4x4 frags.
// LDS: A 2buf x 16KB, B 2buf x 32KB (= 96 KiB).
// Per K-tile stages: A x1 half, B x2 halves; steady-state vmcnt(2).
#define QUADH(mh, nh)                                                                  \
  _Pragma("unroll") for (int mm = 0; mm < 2; ++mm)                                     \
  _Pragma("unroll") for (int nn = 0; nn < 2; ++nn)                                     \
  _Pragma("unroll") for (int s = 0; s < 2; ++s)                                        \
      acc[(mh)*2 + mm][(nh)*2 + nn] = __builtin_amdgcn_mfma_f32_16x16x32_bf16(         \
          af[(mh)*2 + mm][s], bg[(nh)*2 + nn][s], acc[(mh)*2 + mm][(nh)*2 + nn], 0, 0, 0);

#define PHASE_TAILH(MH, NH)                                      \
  __builtin_amdgcn_s_barrier();                                  \
  asm volatile("s_waitcnt lgkmcnt(0)" ::: "memory");             \
  __builtin_amdgcn_sched_barrier(0);                             \
  __builtin_amdgcn_s_setprio(1);                                 \
  QUADH(MH, NH);                                                 \
  __builtin_amdgcn_s_setprio(0);                                 \
  __builtin_amdgcn_s_barrier();

__device__ __forceinline__ void core8h(const char* Ab, size_t lda2, const char* Bb,
                                       size_t ldb2, int nt, char* sA, char* sB,
                                       f32x4 (&acc)[4][4], int w, int lane) {
  const int wr = w >> 2, wc = w & 3;
  const int fr = lane & 15, foB = (lane >> 4) << 4;
  const int brow = (wc & 1) << 6;
  const char* gB1 = Bb + (size_t)128 * ldb2;
  bf16x8 af[4][2], bg[4][2];

  stage_half(Ab, lda2, 0, sA + 0, w, lane);
  stage_half(Bb, ldb2, 0, sB + 0, w, lane);
  stage_half(gB1, ldb2, 0, sB + 16384, w, lane);
  if (nt > 1) {
    stage_half(Ab, lda2, 128, sA + 16384, w, lane);
    asm volatile("s_waitcnt vmcnt(2)" ::: "memory");
  } else {
    asm volatile("s_waitcnt vmcnt(0)" ::: "memory");
  }
  __builtin_amdgcn_sched_barrier(0);
  __builtin_amdgcn_s_barrier();

  for (int t = 0; t < nt; ++t) {
    const int buf = t & 1;
    const char* cA = sA + buf * 16384;
    const char* cB = sB + buf * 32768 + (wc >> 1) * 16384;
    char* nA = sA + buf * 16384;        // tile t+2, same parity
    char* nB = sB + (buf ^ 1) * 32768;  // tile t+1
    const int kb1 = (t + 1) << 7, kb2 = (t + 2) << 7;
    const bool stB = (t + 1 < nt), stA = (t + 2 < nt);

    // p0: frags m0-1 x n0-1; stage B-h0(t+1)
#pragma unroll
    for (int m = 0; m < 2; ++m)
#pragma unroll
      for (int s = 0; s < 2; ++s)
        af[m][s] = *frag_at(cA, wr * 64 + m * 16 + fr, s * 64 + foB);
#pragma unroll
    for (int n = 0; n < 2; ++n)
#pragma unroll
      for (int s = 0; s < 2; ++s)
        bg[n][s] = *frag_at(cB, brow + n * 16 + fr, s * 64 + foB);
    if (stB) stage_half(Bb, ldb2, kb1, nB + 0, w, lane);
    PHASE_TAILH(0, 0)

    // p1: frags m2-3 x n0-1; stage B-h1(t+1)
#pragma unroll
    for (int m = 2; m < 4; ++m)
#pragma unroll
      for (int s = 0; s < 2; ++s)
        af[m][s] = *frag_at(cA, wr * 64 + m * 16 + fr, s * 64 + foB);
    if (stB) stage_half(gB1, ldb2, kb1, nB + 16384, w, lane);
    PHASE_TAILH(1, 0)

    // p2: frags m0-1 x n2-3; stage A(t+2)
#pragma unroll
    for (int n = 2; n < 4; ++n)
#pragma unroll
      for (int s = 0; s < 2; ++s)
        bg[n][s] = *frag_at(cB, brow + n * 16 + fr, s * 64 + foB);
    if (stA) stage_half(Ab, lda2, kb2, nA, w, lane);
    PHASE_TAILH(0, 1)

    // p3: frags m2-3 x n2-3; per-tile counted vmcnt
    if (t < nt - 1) {
      if (stA) {
        asm volatile("s_waitcnt vmcnt(2)" ::: "memory");
      } else {
        asm volatile("s_waitcnt vmcnt(0)" ::: "memory");
      }
      __builtin_amdgcn_sched_barrier(0);
    }
    PHASE_TAILH(1, 1)
  }
}

#define ACC8_INIT                                    \
  f32x4 acc[8][4];                                   \
  _Pragma("unroll") for (int m_ = 0; m_ < 8; ++m_)   \
  _Pragma("unroll") for (int n_ = 0; n_ < 4; ++n_)   \
      acc[m_][n_] = f32x4{0.f, 0.f, 0.f, 0.f};

#define ACC4_INIT                                    \
  f32x4 acc[4][4];                                   \
  _Pragma("unroll") for (int m_ = 0; m_ < 4; ++m_)   \
  _Pragma("unroll") for (int n_ = 0; n_ < 4; ++n_)   \
      acc[m_][n_] = f32x4{0.f, 0.f, 0.f, 0.f};

// ---- q, kk(+zsum), Kt, Vt in one launch: grid (128, 1, 4) ----
__global__ __launch_bounds__(512, 2) void k8_qkvt(const ushort* __restrict__ xb,
                                                  const ushort* __restrict__ wt,
                                                  ushort* __restrict__ qb,
                                                  ushort* __restrict__ kkb,
                                                  ushort* __restrict__ Kt,
                                                  ushort* __restrict__ Vt,
                                                  float* __restrict__ zsum) {
  extern __shared__ char smem[];
  const int tid = threadIdx.x, w = tid >> 6, lane = tid & 63;
  const int z = blockIdx.z, bx = blockIdx.x;
  const int at = (z < 2) ? (bx >> 1) : (bx & 1);
  const int bt = (z < 2) ? (bx & 1) : (bx >> 1);
  const ushort* wsel = wt + (z == 0 ? 0 : (z == 3 ? 524288 : 262144));  // z1,z2 -> WkT
  const ushort* A = (z < 2) ? (xb + (size_t)at * 131072) : (wsel + (size_t)at * 131072);
  const ushort* Bp = (z < 2) ? (wsel + (size_t)bt * 131072) : (xb + (size_t)bt * 131072);
  ACC8_INIT
  core8((const char*)A, 1024, (const char*)Bp, 1024, 8, smem, smem + 65536, acc, w, lane);
  const int mr = w >> 2, nc = w & 3, fr = lane & 15, q4 = (lane >> 4) << 2;
  const size_t row0 = (size_t)at * 256 + mr * 128;
  const size_t col0 = (size_t)bt * 256 + nc * 64;
  if (z < 2) {
    ushort* C = z ? kkb : qb;
    float zs[4] = {0.f, 0.f, 0.f, 0.f};
#pragma unroll
    for (int m = 0; m < 8; ++m)
#pragma unroll
      for (int n = 0; n < 4; ++n)
#pragma unroll
        for (int r = 0; r < 4; ++r) {
          float v = acc[m][n][r];
          v = v > 0.f ? v + 1.f : __expf(v);
          C[(row0 + m * 16 + q4 + r) * 512 + col0 + n * 16 + fr] = bfbits(v);
          zs[n] += v;
        }
    if (z == 1) {
      float* zbuf = (float*)smem;
#pragma unroll
      for (int n = 0; n < 4; ++n) {
        zs[n] += __shfl_xor(zs[n], 16, 64);
        zs[n] += __shfl_xor(zs[n], 32, 64);
        if (lane < 16) zbuf[mr * 256 + nc * 64 + n * 16 + fr] = zs[n];
      }
      __syncthreads();
      if (tid < 256) zsum[(size_t)at * 512 + bt * 256 + tid] = zbuf[tid] + zbuf[256 + tid];
    }
  } else {
    ushort* C = (z == 2) ? Kt : Vt;
    const bool phi = (z == 2);
#pragma unroll
    for (int m = 0; m < 8; ++m)
#pragma unroll
      for (int n = 0; n < 4; ++n)
#pragma unroll
        for (int r = 0; r < 4; ++r) {
          float v = acc[m][n][r];
          if (phi) v = v > 0.f ? v + 1.f : __expf(v);
          C[(row0 + m * 16 + q4 + r) * 16384 + col0 + n * 16 + fr] = bfbits(v);
        }
  }
}

// ---- Mt (256 blocks, 256-core) + G (128 blocks, 128-core) in one launch ----
__global__ __launch_bounds__(512, 2) void k8_MG(const ushort* __restrict__ Kt,
                                                const ushort* __restrict__ Vt,
                                                const ushort* __restrict__ qb,
                                                const ushort* __restrict__ kkb,
                                                ushort* __restrict__ Mt,
                                                ushort* __restrict__ G) {
  extern __shared__ char smem[];
  const int tid = threadIdx.x, w = tid >> 6, lane = tid & 63;
  const int bx = blockIdx.x;
  if (bx < 256) {  // Mt_c = Vt_c Kt_c^T
    const int bc = bx >> 2, rt = bx & 1, ct = (bx >> 1) & 1;
    const ushort* A = Vt + (size_t)bc * 256 + (size_t)rt * 256 * 16384;
    const ushort* Bp = Kt + (size_t)bc * 256 + (size_t)ct * 256 * 16384;
    ACC8_INIT
    core8((const char*)A, 32768, (const char*)Bp, 32768, 4, smem, smem + 65536, acc, w, lane);
    ushort* C = Mt + (size_t)bc * 262144;
    const int mr = w >> 2, nc = w & 3, fr = lane & 15, q4 = (lane >> 4) << 2;
    const size_t row0 = (size_t)rt * 256 + mr * 128;
    const size_t col0 = (size_t)ct * 256 + nc * 64;
#pragma unroll
    for (int m = 0; m < 8; ++m)
#pragma unroll
      for (int n = 0; n < 4; ++n)
#pragma unroll
        for (int r = 0; r < 4; ++r)
          C[(row0 + m * 16 + q4 + r) * 512 + col0 + n * 16 + fr] = bfbits(acc[m][n][r]);
  } else {  // G = tril(Q_c K_c^T), 128-row tiles, full 256 cols
    const int g = bx - 256;
    const int bc = g >> 1, rh = g & 1;
    const ushort* A = qb + (size_t)bc * 131072 + (size_t)rh * 65536;
    const ushort* Bp = kkb + (size_t)bc * 131072;
    ACC4_INIT
    core8h((const char*)A, 1024, (const char*)Bp, 1024, 8, smem, smem + 32768, acc, w, lane);
    ushort* Gc = G + (size_t)bc * 65536;
    const int wr = w >> 2, wc = w & 3, fr = lane & 15, q4 = (lane >> 4) << 2;
#pragma unroll
    for (int m = 0; m < 4; ++m)
#pragma unroll
      for (int n = 0; n < 4; ++n)
#pragma unroll
        for (int r = 0; r < 4; ++r) {
          int row = rh * 128 + wr * 64 + m * 16 + q4 + r;
          int col = wc * 64 + n * 16 + fr;
          float v = (col <= row) ? acc[m][n][r] : 0.f;
          Gc[(size_t)row * 256 + col] = bfbits(v);
        }
  }
}

// ---- den (4096 blocks) + chunk-prefix of Mt (1024 blocks) ----
__global__ __launch_bounds__(256) void k_dp(const ushort* __restrict__ q,
                                            const ushort* __restrict__ G,
                                            const float* __restrict__ zsum,
                                            ushort* __restrict__ Mt,
                                            float* __restrict__ den) {
  if (blockIdx.x < 4096) {
    const int l = threadIdx.x & 63;
    const int bt = blockIdx.x * 4 + (threadIdx.x >> 6);
    const int b = bt >> 11, t = bt & 2047, c = t >> 8, tl = t & 255;
    const int bc = b * 8 + c;
    const int d0 = l * 8;
    float zp[8] = {0.f, 0.f, 0.f, 0.f, 0.f, 0.f, 0.f, 0.f};
    for (int cp = 0; cp < c; ++cp) {
      const float* zr = zsum + (size_t)(b * 8 + cp) * 512 + d0;
      float4 a0 = *(const float4*)zr, a1 = *(const float4*)(zr + 4);
      zp[0] += a0.x; zp[1] += a0.y; zp[2] += a0.z; zp[3] += a0.w;
      zp[4] += a1.x; zp[5] += a1.y; zp[6] += a1.z; zp[7] += a1.w;
    }
    ushort8 qv = *(const ushort8*)&q[(size_t)bt * 512 + d0];
    float s = 0.f;
#pragma unroll
    for (int j = 0; j < 8; ++j) s = fmaf(bff(qv[j]), zp[j], s);
    const ushort* grow = G + (size_t)bc * 65536 + (size_t)tl * 256;
    const int limit = (tl & 128) ? 256 : 128;
    for (int ss = l; ss < limit; ss += 64) s += bff(grow[ss]);
#pragma unroll
    for (int off = 32; off >= 1; off >>= 1) s += __shfl_xor(s, off, 64);
    if (l == 0) den[bt] = s + 1e-6f;
  } else {
    const int g = blockIdx.x - 4096;
    const int b = g >> 7, blk = g & 127;
    ushort* base0 = Mt + (size_t)b * 8 * 262144 + (size_t)blk * 2048 + (size_t)threadIdx.x * 8;
    ushort8 mv0 = *(ushort8*)(base0 + 0 * 262144);
    ushort8 mv1 = *(ushort8*)(base0 + 1 * 262144);
    ushort8 mv2 = *(ushort8*)(base0 + 2 * 262144);
    ushort8 mv3 = *(ushort8*)(base0 + 3 * 262144);
    ushort8 mv4 = *(ushort8*)(base0 + 4 * 262144);
    ushort8 mv5 = *(ushort8*)(base0 + 5 * 262144);
    ushort8 mv6 = *(ushort8*)(base0 + 6 * 262144);
    ushort8 mv7 = *(ushort8*)(base0 + 7 * 262144);
    float a[8] = {0.f, 0.f, 0.f, 0.f, 0.f, 0.f, 0.f, 0.f};
    ushort8 ov;
#define PSTEP(c, mv)                                                     \
    _Pragma("unroll") for (int j = 0; j < 8; ++j) {                      \
      ov[j] = bfbits(a[j]); a[j] += bff(mv[j]);                          \
    }                                                                    \
    *(ushort8*)(base0 + c * 262144) = ov;
    PSTEP(0, mv0) PSTEP(1, mv1) PSTEP(2, mv2) PSTEP(3, mv3)
    PSTEP(4, mv4) PSTEP(5, mv5) PSTEP(6, mv6) PSTEP(7, mv7)
#undef PSTEP
  }
}

// ---- y = (Q St^T + G Vt^T)/den : grid (4, 64), 128-core ----
__global__ __launch_bounds__(512, 2) void k8_y(const ushort* __restrict__ qb,
                                               const ushort* __restrict__ G,
                                               const ushort* __restrict__ Mt,
                                               const ushort* __restrict__ Vt,
                                               const float* __restrict__ den,
                                               ushort* __restrict__ Y) {
  extern __shared__ char smem[];
  const int tid = threadIdx.x, w = tid >> 6, lane = tid & 63;
  const int rh = blockIdx.x & 1, ch = blockIdx.x >> 1, bc = blockIdx.y;
  ACC4_INIT
  core8h((const char*)(qb + (size_t)bc * 131072 + (size_t)rh * 65536), 1024,
         (const char*)(Mt + (size_t)bc * 262144 + (size_t)ch * 131072), 1024, 8,
         smem, smem + 32768, acc, w, lane);
  // intra-chunk: rows < 128 only need K=128 of G (upper cols are zero)
  core8h((const char*)(G + (size_t)bc * 65536 + (size_t)rh * 32768), 512,
         (const char*)(Vt + (size_t)ch * 256 * 16384 + (size_t)bc * 256), 32768,
         rh ? 4 : 2, smem, smem + 32768, acc, w, lane);
  const int wr = w >> 2, wc = w & 3, fr = lane & 15, q4 = (lane >> 4) << 2;
#pragma unroll
  for (int m = 0; m < 4; ++m)
#pragma unroll
    for (int n = 0; n < 4; ++n)
#pragma unroll
      for (int r = 0; r < 4; ++r) {
        size_t row = (size_t)bc * 256 + rh * 128 + wr * 64 + m * 16 + q4 + r;
        size_t col = (size_t)ch * 256 + wc * 64 + n * 16 + fr;
        float v = acc[m][n][r] / den[row];
        Y[row * 512 + col] = bfbits(v);
      }
}

// ---- out = Y WpT^T (fp32) : grid (128, 2), 128-core ----
__global__ __launch_bounds__(512, 2) void k8_out(const ushort* __restrict__ Y,
                                                 const ushort* __restrict__ wt,
                                                 float* __restrict__ out) {
  extern __shared__ char smem[];
  const int tid = threadIdx.x, w = tid >> 6, lane = tid & 63;
  ACC4_INIT
  core8h((const char*)(Y + (size_t)blockIdx.x * 65536), 1024,
         (const char*)(wt + 786432 + (size_t)blockIdx.y * 131072), 1024, 8,
         smem, smem + 32768, acc, w, lane);
  const int wr = w >> 2, wc = w & 3, fr = lane & 15, q4 = (lane >> 4) << 2;
  const size_t row0 = (size_t)blockIdx.x * 128 + wr * 64;
  const size_t col0 = (size_t)blockIdx.y * 256 + wc * 64;
#pragma unroll
  for (int m = 0; m < 4; ++m)
#pragma unroll
    for (int n = 0; n < 4; ++n)
#pragma unroll
      for (int r = 0; r < 4; ++r)
        out[(row0 + m * 16 + q4 + r) * 512 + col0 + n * 16 + fr] = acc[m][n][r];
}

// ---- x -> bf16 (4096 blocks) + W -> W^T bf16 (256 blocks) ----
__global__ __launch_bounds__(256) void k_pre(const float* __restrict__ x,
                                             const float* __restrict__ Wq,
                                             const float* __restrict__ Wk,
                                             const float* __restrict__ Wv,
                                             const float* __restrict__ Wp,
                                             ushort* __restrict__ xb,
                                             ushort* __restrict__ wt) {
  __shared__ float tile[64][65];
  if (blockIdx.x < 4096) {
    size_t i = ((size_t)blockIdx.x * 256 + threadIdx.x) * 8;
    float4 f0 = *(const float4*)&x[i], f1 = *(const float4*)&x[i + 4];
    ushort8 o;
    o[0] = bfbits(f0.x); o[1] = bfbits(f0.y); o[2] = bfbits(f0.z); o[3] = bfbits(f0.w);
    o[4] = bfbits(f1.x); o[5] = bfbits(f1.y); o[6] = bfbits(f1.z); o[7] = bfbits(f1.w);
    *(ushort8*)&xb[i] = o;
  } else {
    const int g = blockIdx.x - 4096;
    const int bz = g >> 6, rem = g & 63, bxw = rem >> 3, byw = rem & 7;
    const float* src = bz == 0 ? Wq : bz == 1 ? Wk : bz == 2 ? Wv : Wp;
    ushort* dst = wt + (size_t)bz * 262144;
    const int d0 = bxw * 64, n0 = byw * 64;
    const int tr = threadIdx.x >> 4, tc = (threadIdx.x & 15) << 2;
#pragma unroll
    for (int it = 0; it < 4; ++it) {
      float4 f = *(const float4*)&src[(size_t)(d0 + it * 16 + tr) * 512 + n0 + tc];
      tile[it * 16 + tr][tc + 0] = f.x;
      tile[it * 16 + tr][tc + 1] = f.y;
      tile[it * 16 + tr][tc + 2] = f.z;
      tile[it * 16 + tr][tc + 3] = f.w;
    }
    __syncthreads();
#pragma unroll
    for (int it = 0; it < 4; ++it) {
      int n = it * 16 + tr;
      ushort4 o;
      o.x = bfbits(tile[tc + 0][n]);
      o.y = bfbits(tile[tc + 1][n]);
      o.z = bfbits(tile[tc + 2][n]);
      o.w = bfbits(tile[tc + 3][n]);
      *(ushort4*)&dst[(size_t)(n0 + n) * 512 + d0 + tc] = o;
    }
  }
}

extern "C" void kernel_launch(void* const* d_in, const int* in_sizes, int n_in,
                              void* d_out, int out_size, void* d_ws, size_t ws_size,
                              hipStream_t stream) {
  const float* x  = (const float*)d_in[0];
  const float* Wq = (const float*)d_in[1];
  const float* Wk = (const float*)d_in[2];
  const float* Wv = (const float*)d_in[3];
  const float* Wp = (const float*)d_in[4];
  float* out = (float*)d_out;
  char* ws8 = (char*)d_ws;
  if (ws_size < WS_NEED) return;

  ushort* xb  = (ushort*)(ws8 + OFF_XB);
  ushort* wt  = (ushort*)(ws8 + OFF_WT);
  ushort* qb  = (ushort*)(ws8 + OFF_Q);
  ushort* kkb = (ushort*)(ws8 + OFF_KK);
  ushort* Kt  = (ushort*)(ws8 + OFF_KT);
  ushort* Vt  = (ushort*)(ws8 + OFF_VT);
  ushort* G   = (ushort*)(ws8 + OFF_G);
  ushort* Mt  = (ushort*)(ws8 + OFF_MT);
  ushort* Y   = (ushort*)(ws8 + OFF_Y);
  float*  zp  = (float*)(ws8 + OFF_ZP);
  float*  den = (float*)(ws8 + OFF_DEN);

  constexpr int SMEM_BIG = 131072, SMEM_H = 98304;
  hipFuncSetAttribute((const void*)k8_qkvt, hipFuncAttributeMaxDynamicSharedMemorySize, SMEM_BIG);
  hipFuncSetAttribute((const void*)k8_MG,   hipFuncAttributeMaxDynamicSharedMemorySize, SMEM_BIG);
  hipFuncSetAttribute((const void*)k8_y,    hipFuncAttributeMaxDynamicSharedMemorySize, SMEM_H);
  hipFuncSetAttribute((const void*)k8_out,  hipFuncAttributeMaxDynamicSharedMemorySize, SMEM_H);

  k_pre<<<4352, 256, 0, stream>>>(x, Wq, Wk, Wv, Wp, xb, wt);
  k8_qkvt<<<dim3(128, 1, 4), 512, SMEM_BIG, stream>>>(xb, wt, qb, kkb, Kt, Vt, zp);
  k8_MG<<<384, 512, SMEM_BIG, stream>>>(Kt, Vt, qb, kkb, Mt, G);
  k_dp<<<5120, 256, 0, stream>>>(qb, G, zp, Mt, den);
  k8_y<<<dim3(4, 64), 512, SMEM_H, stream>>>(qb, G, Mt, Vt, den, Y);
  k8_out<<<dim3(128, 2), 512, SMEM_H, stream>>>(Y, wt, out);
}

// Round 5
// 144.899 us; speedup vs baseline: 6.4143x; 1.0738x over previous
//
#include <hip/hip_runtime.h>

// Linear attention (B=8, T=2048, D=512), chunked, bf16 MFMA, fp32 acc.
// R5: six launches.
//   k_pre    : bf16(x) + W^T transposes                         (4352 blocks)
//   k8_qkvt  : q | kk + Kt^T(+zsum) | Vt^T  (core8h, 3 rounds)  (768 blocks)
//   k8_MG    : Mt = Vt_c Kt_c^T  and  G = tril(QK^T) + den      (384 blocks)
//   k_prefix : chunk-prefix of Mt (in place)                    (1024 blocks)
//   k8_y     : y = (Q St^T + G Vt^T)/den                        (256 blocks)
//   k8_out   : out = y Wp^T (fp32)                              (256 blocks)
// All GEMMs are C = A * B^T with A:[M][K], B:[N][K] row-major bf16.
// Kt/Vt are produced by TRANSPOSED EPILOGUE STORES (ushort4 along the
// MFMA C-fragment's 4-consecutive-row axis), not by separate GEMMs.

typedef __attribute__((ext_vector_type(4))) float f32x4;
typedef __attribute__((ext_vector_type(8))) __bf16 bf16x8;
typedef __attribute__((ext_vector_type(8))) unsigned short ushort8;

// ---- ws layout (byte offsets) ----
constexpr size_t OFF_XB  = 0;                  // bf16 [16384][512]
constexpr size_t OFF_WT  = OFF_XB + 16777216;  // bf16 4x [512][512] (WqT,WkT,WvT,WpT)
constexpr size_t OFF_Q   = OFF_WT + 2097152;   // bf16 [16384][512]
constexpr size_t OFF_KK  = OFF_Q  + 16777216;  // bf16 [16384][512]
constexpr size_t OFF_KT  = OFF_KK + 16777216;  // bf16 [512][16384]
constexpr size_t OFF_VT  = OFF_KT + 16777216;  // bf16 [512][16384]
constexpr size_t OFF_G   = OFF_VT + 16777216;  // bf16 [64][256][256]
constexpr size_t OFF_MT  = OFF_G  + 8388608;   // bf16 [64][512][512] (becomes St)
constexpr size_t OFF_Y   = OFF_MT + 33554432;  // bf16 [16384][512]
constexpr size_t OFF_ZP  = OFF_Y  + 16777216;  // f32  [128][512] half-chunk col sums of kk
constexpr size_t OFF_DEN = OFF_ZP + 262144;    // f32  [16384]
constexpr size_t WS_NEED = OFF_DEN + 65536;

__device__ __forceinline__ unsigned short bfbits(float f) {
  __bf16 h = (__bf16)f;
  return __builtin_bit_cast(unsigned short, h);
}
__device__ __forceinline__ float bff(unsigned short u) {
  return (float)__builtin_bit_cast(__bf16, u);
}

__device__ __forceinline__ void gload16(const void* g, void* l) {
  __builtin_amdgcn_global_load_lds((const __attribute__((address_space(1))) void*)g,
                                   (__attribute__((address_space(3))) void*)l, 16, 0, 0);
}

// Stage one 128-row x 64-col bf16 half-tile (16 KiB) with 512 threads.
// LDS dest linear; global source pre-swizzled with byte ^= ((row&7)<<4),
// matching frag_at's read-side swizzle (both-sides-or-neither rule).
__device__ __forceinline__ void stage_half(const char* gRow0, size_t ld2, int k0b,
                                           char* ldsHalf, int w, int lane) {
#pragma unroll
  for (int i = 0; i < 2; ++i) {
    int L = (w << 10) + (lane << 4) + (i << 13);
    int r = L >> 7;
    int cb = (L & 127) ^ ((r & 7) << 4);
    gload16(gRow0 + (size_t)r * ld2 + k0b + cb, ldsHalf + (w << 10) + (i << 13));
  }
}

__device__ __forceinline__ const bf16x8* frag_at(const char* halfBase, int rowInHalf,
                                                 int colByte) {
  int lin = (rowInHalf << 7) + colByte;
  lin ^= (rowInHalf & 7) << 4;
  return (const bf16x8*)(halfBase + lin);
}

// ======================= 256x256 8-wave 8-phase core =======================
#define QUAD(mh, nh)                                                                   \
  _Pragma("unroll") for (int mm = 0; mm < 4; ++mm)                                     \
  _Pragma("unroll") for (int nn = 0; nn < 2; ++nn)                                     \
  _Pragma("unroll") for (int s = 0; s < 2; ++s)                                        \
      acc[(mh)*4 + mm][(nh)*2 + nn] = __builtin_amdgcn_mfma_f32_16x16x32_bf16(         \
          af[(mh)*4 + mm][s], bg[(nh)*2 + nn][s], acc[(mh)*4 + mm][(nh)*2 + nn], 0, 0, 0);

#define PHASE_TAIL(MH, NH)                                       \
  __builtin_amdgcn_s_barrier();                                  \
  asm volatile("s_waitcnt lgkmcnt(0)" ::: "memory");             \
  __builtin_amdgcn_sched_barrier(0);                             \
  __builtin_amdgcn_s_setprio(1);                                 \
  QUAD(MH, NH);                                                  \
  __builtin_amdgcn_s_setprio(0);                                 \
  __builtin_amdgcn_s_barrier();

__device__ __forceinline__ void core8(const char* Ab, size_t lda2, const char* Bb,
                                      size_t ldb2, int nt, char* sA, char* sB,
                                      f32x4 (&acc)[8][4], int w, int lane) {
  const int mr = w >> 2, nc = w & 3;
  const int fr = lane & 15, foB = (lane >> 4) << 4;
  const int brow = (nc & 1) << 6;
  const char* gA0 = Ab;
  const char* gA1 = Ab + (size_t)128 * lda2;
  const char* gB0 = Bb;
  const char* gB1 = Bb + (size_t)128 * ldb2;
  bf16x8 af[8][2], bg[4][2];

  stage_half(gA0, lda2, 0, sA + 0 * 16384, w, lane);
  stage_half(gA1, lda2, 0, sA + 1 * 16384, w, lane);
  stage_half(gB0, ldb2, 0, sB + 0 * 16384, w, lane);
  stage_half(gB1, ldb2, 0, sB + 1 * 16384, w, lane);
  if (nt > 1) {
    stage_half(gA0, lda2, 128, sA + 2 * 16384, w, lane);
    stage_half(gA1, lda2, 128, sA + 3 * 16384, w, lane);
    asm volatile("s_waitcnt vmcnt(4)" ::: "memory");
  } else {
    asm volatile("s_waitcnt vmcnt(0)" ::: "memory");
  }
  __builtin_amdgcn_sched_barrier(0);
  __builtin_amdgcn_s_barrier();

  for (int t = 0; t < nt; ++t) {
    const int buf = t & 1;
    const char* cA = sA + buf * 32768 + mr * 16384;
    const char* cB = sB + buf * 32768 + (nc >> 1) * 16384;
    char* nA = sA + buf * 32768;
    char* nB = sB + (buf ^ 1) * 32768;
    const int kb1 = (t + 1) << 7, kb2 = (t + 2) << 7;
    const bool stB = (t + 1 < nt), stA = (t + 2 < nt);

#pragma unroll
    for (int m = 0; m < 4; ++m)
#pragma unroll
      for (int s = 0; s < 2; ++s) af[m][s] = *frag_at(cA, m * 16 + fr, s * 64 + foB);
#pragma unroll
    for (int n = 0; n < 2; ++n)
#pragma unroll
      for (int s = 0; s < 2; ++s)
        bg[n][s] = *frag_at(cB, brow + n * 16 + fr, s * 64 + foB);
    if (stB) stage_half(gB0, ldb2, kb1, nB + 0 * 16384, w, lane);
    PHASE_TAIL(0, 0)

#pragma unroll
    for (int m = 4; m < 8; ++m)
#pragma unroll
      for (int s = 0; s < 2; ++s) af[m][s] = *frag_at(cA, m * 16 + fr, s * 64 + foB);
    if (stB) stage_half(gB1, ldb2, kb1, nB + 1 * 16384, w, lane);
    PHASE_TAIL(1, 0)

#pragma unroll
    for (int n = 2; n < 4; ++n)
#pragma unroll
      for (int s = 0; s < 2; ++s)
        bg[n][s] = *frag_at(cB, brow + n * 16 + fr, s * 64 + foB);
    if (stA) stage_half(gA0, lda2, kb2, nA + 0 * 16384, w, lane);
    PHASE_TAIL(0, 1)

    if (stA) stage_half(gA1, lda2, kb2, nA + 1 * 16384, w, lane);
    if (t < nt - 2) {
      asm volatile("s_waitcnt vmcnt(4)" ::: "memory");
      __builtin_amdgcn_sched_barrier(0);
    } else if (t == nt - 2) {
      asm volatile("s_waitcnt vmcnt(0)" ::: "memory");
      __builtin_amdgcn_sched_barrier(0);
    }
    PHASE_TAIL(1, 1)
  }
}

// ======================= 128x256 8-wave 4-phase core =======================
#define QUADH(mh, nh)                                                                  \
  _Pragma("unroll") for (int mm = 0; mm < 2; ++mm)                                     \
  _Pragma("unroll") for (int nn = 0; nn < 2; ++nn)                                     \
  _Pragma("unroll") for (int s = 0; s < 2; ++s)                                        \
      acc[(mh)*2 + mm][(nh)*2 + nn] = __builtin_amdgcn_mfma_f32_16x16x32_bf16(         \
          af[(mh)*2 + mm][s], bg[(nh)*2 + nn][s], acc[(mh)*2 + mm][(nh)*2 + nn], 0, 0, 0);

#define PHASE_TAILH(MH, NH)                                      \
  __builtin_amdgcn_s_barrier();                                  \
  asm volatile("s_waitcnt lgkmcnt(0)" ::: "memory");             \
  __builtin_amdgcn_sched_barrier(0);                             \
  __builtin_amdgcn_s_setprio(1);                                 \
  QUADH(MH, NH);                                                 \
  __builtin_amdgcn_s_setprio(0);                                 \
  __builtin_amdgcn_s_barrier();

__device__ __forceinline__ void core8h(const char* Ab, size_t lda2, const char* Bb,
                                       size_t ldb2, int nt, char* sA, char* sB,
                                       f32x4 (&acc)[4][4], int w, int lane) {
  const int wr = w >> 2, wc = w & 3;
  const int fr = lane & 15, foB = (lane >> 4) << 4;
  const int brow = (wc & 1) << 6;
  const char* gB1 = Bb + (size_t)128 * ldb2;
  bf16x8 af[4][2], bg[4][2];

  stage_half(Ab, lda2, 0, sA + 0, w, lane);
  stage_half(Bb, ldb2, 0, sB + 0, w, lane);
  stage_half(gB1, ldb2, 0, sB + 16384, w, lane);
  if (nt > 1) {
    stage_half(Ab, lda2, 128, sA + 16384, w, lane);
    asm volatile("s_waitcnt vmcnt(2)" ::: "memory");
  } else {
    asm volatile("s_waitcnt vmcnt(0)" ::: "memory");
  }
  __builtin_amdgcn_sched_barrier(0);
  __builtin_amdgcn_s_barrier();

  for (int t = 0; t < nt; ++t) {
    const int buf = t & 1;
    const char* cA = sA + buf * 16384;
    const char* cB = sB + buf * 32768 + (wc >> 1) * 16384;
    char* nA = sA + buf * 16384;
    char* nB = sB + (buf ^ 1) * 32768;
    const int kb1 = (t + 1) << 7, kb2 = (t + 2) << 7;
    const bool stB = (t + 1 < nt), stA = (t + 2 < nt);

#pragma unroll
    for (int m = 0; m < 2; ++m)
#pragma unroll
      for (int s = 0; s < 2; ++s)
        af[m][s] = *frag_at(cA, wr * 64 + m * 16 + fr, s * 64 + foB);
#pragma unroll
    for (int n = 0; n < 2; ++n)
#pragma unroll
      for (int s = 0; s < 2; ++s)
        bg[n][s] = *frag_at(cB, brow + n * 16 + fr, s * 64 + foB);
    if (stB) stage_half(Bb, ldb2, kb1, nB + 0, w, lane);
    PHASE_TAILH(0, 0)

#pragma unroll
    for (int m = 2; m < 4; ++m)
#pragma unroll
      for (int s = 0; s < 2; ++s)
        af[m][s] = *frag_at(cA, wr * 64 + m * 16 + fr, s * 64 + foB);
    if (stB) stage_half(gB1, ldb2, kb1, nB + 16384, w, lane);
    PHASE_TAILH(1, 0)

#pragma unroll
    for (int n = 2; n < 4; ++n)
#pragma unroll
      for (int s = 0; s < 2; ++s)
        bg[n][s] = *frag_at(cB, brow + n * 16 + fr, s * 64 + foB);
    if (stA) stage_half(Ab, lda2, kb2, nA, w, lane);
    PHASE_TAILH(0, 1)

    if (t < nt - 1) {
      if (stA) {
        asm volatile("s_waitcnt vmcnt(2)" ::: "memory");
      } else {
        asm volatile("s_waitcnt vmcnt(0)" ::: "memory");
      }
      __builtin_amdgcn_sched_barrier(0);
    }
    PHASE_TAILH(1, 1)
  }
}

#define ACC8_INIT                                    \
  f32x4 acc[8][4];                                   \
  _Pragma("unroll") for (int m_ = 0; m_ < 8; ++m_)   \
  _Pragma("unroll") for (int n_ = 0; n_ < 4; ++n_)   \
      acc[m_][n_] = f32x4{0.f, 0.f, 0.f, 0.f};

#define ACC4_INIT                                    \
  f32x4 acc[4][4];                                   \
  _Pragma("unroll") for (int m_ = 0; m_ < 4; ++m_)   \
  _Pragma("unroll") for (int n_ = 0; n_ < 4; ++n_)   \
      acc[m_][n_] = f32x4{0.f, 0.f, 0.f, 0.f};

// ---- q | kk+Kt^T(+zsum halves) | Vt^T : grid (128 mt, 2 ct, 3 z) ----
__global__ __launch_bounds__(512, 2) void k8_qkvt(const ushort* __restrict__ xb,
                                                  const ushort* __restrict__ wt,
                                                  ushort* __restrict__ qb,
                                                  ushort* __restrict__ kkb,
                                                  ushort* __restrict__ Kt,
                                                  ushort* __restrict__ Vt,
                                                  float* __restrict__ zsumH) {
  extern __shared__ char smem[];
  const int tid = threadIdx.x, w = tid >> 6, lane = tid & 63;
  const int z = blockIdx.z, mt = blockIdx.x, ct = blockIdx.y;
  const ushort* wsel = wt + (z == 0 ? 0 : (z == 1 ? 262144 : 524288));
  const ushort* A = xb + (size_t)mt * 128 * 512;
  const ushort* Bp = wsel + (size_t)ct * 256 * 512;
  ACC4_INIT
  core8h((const char*)A, 1024, (const char*)Bp, 1024, 8, smem, smem + 32768, acc, w, lane);
  const int wr = w >> 2, wc = w & 3, fr = lane & 15, q4 = (lane >> 4) << 2;
  const size_t row0 = (size_t)mt * 128 + wr * 64;  // t
  const size_t col0 = (size_t)ct * 256 + wc * 64;  // d
  if (z == 0) {  // q = phi(..), normal layout
#pragma unroll
    for (int m = 0; m < 4; ++m)
#pragma unroll
      for (int n = 0; n < 4; ++n)
#pragma unroll
        for (int r = 0; r < 4; ++r) {
          float v = acc[m][n][r];
          v = v > 0.f ? v + 1.f : __expf(v);
          qb[(row0 + m * 16 + q4 + r) * 512 + col0 + n * 16 + fr] = bfbits(v);
        }
  } else if (z == 2) {  // v -> Vt only (transposed ushort4, no phi)
#pragma unroll
    for (int m = 0; m < 4; ++m)
#pragma unroll
      for (int n = 0; n < 4; ++n) {
        ushort4 o;
        o.x = bfbits(acc[m][n][0]);
        o.y = bfbits(acc[m][n][1]);
        o.z = bfbits(acc[m][n][2]);
        o.w = bfbits(acc[m][n][3]);
        *(ushort4*)&Vt[(col0 + n * 16 + fr) * 16384 + row0 + m * 16 + q4] = o;
      }
  } else {  // z==1: kk normal + Kt transposed + half-chunk col sums
    float zs[4] = {0.f, 0.f, 0.f, 0.f};
#pragma unroll
    for (int m = 0; m < 4; ++m)
#pragma unroll
      for (int n = 0; n < 4; ++n) {
        float ph[4];
#pragma unroll
        for (int r = 0; r < 4; ++r) {
          float v = acc[m][n][r];
          ph[r] = v > 0.f ? v + 1.f : __expf(v);
          kkb[(row0 + m * 16 + q4 + r) * 512 + col0 + n * 16 + fr] = bfbits(ph[r]);
          zs[n] += ph[r];
        }
        ushort4 o;
        o.x = bfbits(ph[0]); o.y = bfbits(ph[1]); o.z = bfbits(ph[2]); o.w = bfbits(ph[3]);
        *(ushort4*)&Kt[(col0 + n * 16 + fr) * 16384 + row0 + m * 16 + q4] = o;
      }
#pragma unroll
    for (int n = 0; n < 4; ++n) {
      zs[n] += __shfl_xor(zs[n], 16, 64);
      zs[n] += __shfl_xor(zs[n], 32, 64);
    }
    float* zbuf = (float*)smem;  // [2 wr][256 cols]; core8h's final barrier protects
    if (lane < 16) {
#pragma unroll
      for (int n = 0; n < 4; ++n) zbuf[wr * 256 + wc * 64 + n * 16 + fr] = zs[n];
    }
    __syncthreads();
    if (tid < 256)
      zsumH[(size_t)mt * 512 + ct * 256 + tid] = zbuf[tid] + zbuf[256 + tid];
  }
}

// ---- Mt (256 blocks, core8) + G+den (128 blocks, core8h) ----
__global__ __launch_bounds__(512, 2) void k8_MG(const ushort* __restrict__ Kt,
                                                const ushort* __restrict__ Vt,
                                                const ushort* __restrict__ qb,
                                                const ushort* __restrict__ kkb,
                                                const float* __restrict__ zsumH,
                                                ushort* __restrict__ Mt,
                                                ushort* __restrict__ G,
                                                float* __restrict__ den) {
  extern __shared__ char smem[];
  const int tid = threadIdx.x, w = tid >> 6, lane = tid & 63;
  const int bx = blockIdx.x;
  if (bx < 256) {  // Mt_c = Vt_c Kt_c^T
    const int bc = bx >> 2, rt = bx & 1, ctl = (bx >> 1) & 1;
    const ushort* A = Vt + (size_t)bc * 256 + (size_t)rt * 256 * 16384;
    const ushort* Bp = Kt + (size_t)bc * 256 + (size_t)ctl * 256 * 16384;
    ACC8_INIT
    core8((const char*)A, 32768, (const char*)Bp, 32768, 4, smem, smem + 65536, acc, w, lane);
    ushort* C = Mt + (size_t)bc * 262144;
    const int mr = w >> 2, nc = w & 3, fr = lane & 15, q4 = (lane >> 4) << 2;
    const size_t row0 = (size_t)rt * 256 + mr * 128;
    const size_t col0 = (size_t)ctl * 256 + nc * 64;
#pragma unroll
    for (int m = 0; m < 8; ++m)
#pragma unroll
      for (int n = 0; n < 4; ++n)
#pragma unroll
        for (int r = 0; r < 4; ++r)
          C[(row0 + m * 16 + q4 + r) * 512 + col0 + n * 16 + fr] = bfbits(acc[m][n][r]);
  } else {  // G = tril(Q_c K_c^T) + den
    const int g = bx - 256;
    const int bc = g >> 1, rh = g & 1;
    const int b = bc >> 3, c = bc & 7;
    const ushort* A = qb + (size_t)bc * 131072 + (size_t)rh * 65536;
    const ushort* Bp = kkb + (size_t)bc * 131072;
    ACC4_INIT
    core8h((const char*)A, 1024, (const char*)Bp, 1024, 8, smem, smem + 32768, acc, w, lane);
    ushort* Gc = G + (size_t)bc * 65536;
    const int wr = w >> 2, wc = w & 3, fr = lane & 15, q4 = (lane >> 4) << 2;
    float rs[4][4];
#pragma unroll
    for (int m = 0; m < 4; ++m)
#pragma unroll
      for (int r = 0; r < 4; ++r) rs[m][r] = 0.f;
#pragma unroll
    for (int m = 0; m < 4; ++m)
#pragma unroll
      for (int n = 0; n < 4; ++n)
#pragma unroll
        for (int r = 0; r < 4; ++r) {
          int row = rh * 128 + wr * 64 + m * 16 + q4 + r;
          int col = wc * 64 + n * 16 + fr;
          float v = (col <= row) ? acc[m][n][r] : 0.f;
          Gc[(size_t)row * 256 + col] = bfbits(v);
          rs[m][r] += v;
        }
#pragma unroll
    for (int m = 0; m < 4; ++m)
#pragma unroll
      for (int r = 0; r < 4; ++r) {
        rs[m][r] += __shfl_xor(rs[m][r], 1, 64);
        rs[m][r] += __shfl_xor(rs[m][r], 2, 64);
        rs[m][r] += __shfl_xor(rs[m][r], 4, 64);
        rs[m][r] += __shfl_xor(rs[m][r], 8, 64);
      }
    float* red = (float*)smem;  // [4 wc][128 rows] partial rowsums
    float* zpl = red + 512;     // [512] zpre for this chunk
    if (fr == 0) {
      int rbase = wr * 64 + q4;
#pragma unroll
      for (int m = 0; m < 4; ++m)
#pragma unroll
        for (int r = 0; r < 4; ++r) red[wc * 128 + rbase + m * 16 + r] = rs[m][r];
    }
    {  // zpre[d] = sum over prior chunks of (both halves of zsumH)
      float a = 0.f;
      for (int cp = 0; cp < c; ++cp)
        a += zsumH[(size_t)((b * 8 + cp) * 2) * 512 + tid] +
             zsumH[(size_t)((b * 8 + cp) * 2 + 1) * 512 + tid];
      zpl[tid] = a;
    }
    __syncthreads();
    {  // den[t] = q_t . zpre + rowsum(tril G) + eps ; 4 threads per row
      int rl = tid >> 2, quarter = tid & 3;
      int trow = bc * 256 + rh * 128 + rl;
      const ushort* qrow = qb + (size_t)trow * 512 + quarter * 128;
      const float* zq = zpl + quarter * 128;
      float s = 0.f;
      for (int j = 0; j < 128; j += 8) {
        ushort8 qv = *(const ushort8*)&qrow[j];
#pragma unroll
        for (int u = 0; u < 8; ++u) s = fmaf(bff(qv[u]), zq[j + u], s);
      }
      s += __shfl_xor(s, 1, 64);
      s += __shfl_xor(s, 2, 64);
      if (quarter == 0)
        den[trow] = s + red[rl] + red[128 + rl] + red[256 + rl] + red[384 + rl] + 1e-6f;
    }
  }
}

// ---- in-place exclusive chunk-prefix of Mt ----
__global__ __launch_bounds__(256) void k_prefix(ushort* __restrict__ Mt) {
  const int g = blockIdx.x;
  const int b = g >> 7, blk = g & 127;
  ushort* base0 = Mt + (size_t)b * 8 * 262144 + (size_t)blk * 2048 + (size_t)threadIdx.x * 8;
  ushort8 mv0 = *(ushort8*)(base0 + 0 * 262144);
  ushort8 mv1 = *(ushort8*)(base0 + 1 * 262144);
  ushort8 mv2 = *(ushort8*)(base0 + 2 * 262144);
  ushort8 mv3 = *(ushort8*)(base0 + 3 * 262144);
  ushort8 mv4 = *(ushort8*)(base0 + 4 * 262144);
  ushort8 mv5 = *(ushort8*)(base0 + 5 * 262144);
  ushort8 mv6 = *(ushort8*)(base0 + 6 * 262144);
  ushort8 mv7 = *(ushort8*)(base0 + 7 * 262144);
  float a[8] = {0.f, 0.f, 0.f, 0.f, 0.f, 0.f, 0.f, 0.f};
  ushort8 ov;
#define PSTEP(c, mv)                                                   \
  _Pragma("unroll") for (int j = 0; j < 8; ++j) {                      \
    ov[j] = bfbits(a[j]); a[j] += bff(mv[j]);                          \
  }                                                                    \
  *(ushort8*)(base0 + c * 262144) = ov;
  PSTEP(0, mv0) PSTEP(1, mv1) PSTEP(2, mv2) PSTEP(3, mv3)
  PSTEP(4, mv4) PSTEP(5, mv5) PSTEP(6, mv6) PSTEP(7, mv7)
#undef PSTEP
}

// ---- y = (Q St^T + G Vt^T)/den : grid (4, 64), core8h ----
__global__ __launch_bounds__(512, 2) void k8_y(const ushort* __restrict__ qb,
                                               const ushort* __restrict__ G,
                                               const ushort* __restrict__ Mt,
                                               const ushort* __restrict__ Vt,
                                               const float* __restrict__ den,
                                               ushort* __restrict__ Y) {
  extern __shared__ char smem[];
  const int tid = threadIdx.x, w = tid >> 6, lane = tid & 63;
  const int rh = blockIdx.x & 1, ch = blockIdx.x >> 1, bc = blockIdx.y;
  ACC4_INIT
  core8h((const char*)(qb + (size_t)bc * 131072 + (size_t)rh * 65536), 1024,
         (const char*)(Mt + (size_t)bc * 262144 + (size_t)ch * 131072), 1024, 8,
         smem, smem + 32768, acc, w, lane);
  core8h((const char*)(G + (size_t)bc * 65536 + (size_t)rh * 32768), 512,
         (const char*)(Vt + (size_t)ch * 256 * 16384 + (size_t)bc * 256), 32768,
         rh ? 4 : 2, smem, smem + 32768, acc, w, lane);
  const int wr = w >> 2, wc = w & 3, fr = lane & 15, q4 = (lane >> 4) << 2;
#pragma unroll
  for (int m = 0; m < 4; ++m)
#pragma unroll
    for (int n = 0; n < 4; ++n)
#pragma unroll
      for (int r = 0; r < 4; ++r) {
        size_t row = (size_t)bc * 256 + rh * 128 + wr * 64 + m * 16 + q4 + r;
        size_t col = (size_t)ch * 256 + wc * 64 + n * 16 + fr;
        float v = acc[m][n][r] / den[row];
        Y[row * 512 + col] = bfbits(v);
      }
}

// ---- out = Y WpT^T (fp32) : grid (128, 2), core8h ----
__global__ __launch_bounds__(512, 2) void k8_out(const ushort* __restrict__ Y,
                                                 const ushort* __restrict__ wt,
                                                 float* __restrict__ out) {
  extern __shared__ char smem[];
  const int tid = threadIdx.x, w = tid >> 6, lane = tid & 63;
  ACC4_INIT
  core8h((const char*)(Y + (size_t)blockIdx.x * 65536), 1024,
         (const char*)(wt + 786432 + (size_t)blockIdx.y * 131072), 1024, 8,
         smem, smem + 32768, acc, w, lane);
  const int wr = w >> 2, wc = w & 3, fr = lane & 15, q4 = (lane >> 4) << 2;
  const size_t row0 = (size_t)blockIdx.x * 128 + wr * 64;
  const size_t col0 = (size_t)blockIdx.y * 256 + wc * 64;
#pragma unroll
  for (int m = 0; m < 4; ++m)
#pragma unroll
    for (int n = 0; n < 4; ++n)
#pragma unroll
      for (int r = 0; r < 4; ++r)
        out[(row0 + m * 16 + q4 + r) * 512 + col0 + n * 16 + fr] = acc[m][n][r];
}

// ---- x -> bf16 (4096 blocks) + W -> W^T bf16 (256 blocks) ----
__global__ __launch_bounds__(256) void k_pre(const float* __restrict__ x,
                                             const float* __restrict__ Wq,
                                             const float* __restrict__ Wk,
                                             const float* __restrict__ Wv,
                                             const float* __restrict__ Wp,
                                             ushort* __restrict__ xb,
                                             ushort* __restrict__ wt) {
  __shared__ float tile[64][65];
  if (blockIdx.x < 4096) {
    size_t i = ((size_t)blockIdx.x * 256 + threadIdx.x) * 8;
    float4 f0 = *(const float4*)&x[i], f1 = *(const float4*)&x[i + 4];
    ushort8 o;
    o[0] = bfbits(f0.x); o[1] = bfbits(f0.y); o[2] = bfbits(f0.z); o[3] = bfbits(f0.w);
    o[4] = bfbits(f1.x); o[5] = bfbits(f1.y); o[6] = bfbits(f1.z); o[7] = bfbits(f1.w);
    *(ushort8*)&xb[i] = o;
  } else {
    const int g = blockIdx.x - 4096;
    const int bz = g >> 6, rem = g & 63, bxw = rem >> 3, byw = rem & 7;
    const float* src = bz == 0 ? Wq : bz == 1 ? Wk : bz == 2 ? Wv : Wp;
    ushort* dst = wt + (size_t)bz * 262144;
    const int d0 = bxw * 64, n0 = byw * 64;
    const int tr = threadIdx.x >> 4, tc = (threadIdx.x & 15) << 2;
#pragma unroll
    for (int it = 0; it < 4; ++it) {
      float4 f = *(const float4*)&src[(size_t)(d0 + it * 16 + tr) * 512 + n0 + tc];
      tile[it * 16 + tr][tc + 0] = f.x;
      tile[it * 16 + tr][tc + 1] = f.y;
      tile[it * 16 + tr][tc + 2] = f.z;
      tile[it * 16 + tr][tc + 3] = f.w;
    }
    __syncthreads();
#pragma unroll
    for (int it = 0; it < 4; ++it) {
      int n = it * 16 + tr;
      ushort4 o;
      o.x = bfbits(tile[tc + 0][n]);
      o.y = bfbits(tile[tc + 1][n]);
      o.z = bfbits(tile[tc + 2][n]);
      o.w = bfbits(tile[tc + 3][n]);
      *(ushort4*)&dst[(size_t)(n0 + n) * 512 + d0 + tc] = o;
    }
  }
}

extern "C" void kernel_launch(void* const* d_in, const int* in_sizes, int n_in,
                              void* d_out, int out_size, void* d_ws, size_t ws_size,
                              hipStream_t stream) {
  const float* x  = (const float*)d_in[0];
  const float* Wq = (const float*)d_in[1];
  const float* Wk = (const float*)d_in[2];
  const float* Wv = (const float*)d_in[3];
  const float* Wp = (const float*)d_in[4];
  float* out = (float*)d_out;
  char* ws8 = (char*)d_ws;
  if (ws_size < WS_NEED) return;

  ushort* xb  = (ushort*)(ws8 + OFF_XB);
  ushort* wt  = (ushort*)(ws8 + OFF_WT);
  ushort* qb  = (ushort*)(ws8 + OFF_Q);
  ushort* kkb = (ushort*)(ws8 + OFF_KK);
  ushort* Kt  = (ushort*)(ws8 + OFF_KT);
  ushort* Vt  = (ushort*)(ws8 + OFF_VT);
  ushort* G   = (ushort*)(ws8 + OFF_G);
  ushort* Mt  = (ushort*)(ws8 + OFF_MT);
  ushort* Y   = (ushort*)(ws8 + OFF_Y);
  float*  zpH = (float*)(ws8 + OFF_ZP);
  float*  den = (float*)(ws8 + OFF_DEN);

  constexpr int SMEM_BIG = 131072, SMEM_H = 98304;
  hipFuncSetAttribute((const void*)k8_qkvt, hipFuncAttributeMaxDynamicSharedMemorySize, SMEM_H);
  hipFuncSetAttribute((const void*)k8_MG,   hipFuncAttributeMaxDynamicSharedMemorySize, SMEM_BIG);
  hipFuncSetAttribute((const void*)k8_y,    hipFuncAttributeMaxDynamicSharedMemorySize, SMEM_H);
  hipFuncSetAttribute((const void*)k8_out,  hipFuncAttributeMaxDynamicSharedMemorySize, SMEM_H);

  k_pre<<<4352, 256, 0, stream>>>(x, Wq, Wk, Wv, Wp, xb, wt);
  k8_qkvt<<<dim3(128, 2, 3), 512, SMEM_H, stream>>>(xb, wt, qb, kkb, Kt, Vt, zpH);
  k8_MG<<<384, 512, SMEM_BIG, stream>>>(Kt, Vt, qb, kkb, zpH, Mt, G, den);
  k_prefix<<<1024, 256, 0, stream>>>(Mt);
  k8_y<<<dim3(4, 64), 512, SMEM_H, stream>>>(qb, G, Mt, Vt, den, Y);
  k8_out<<<dim3(128, 2), 512, SMEM_H, stream>>>(Y, wt, out);
}

// Round 6
// 135.134 us; speedup vs baseline: 6.8778x; 1.0723x over previous
//
#include <hip/hip_runtime.h>

// Linear attention (B=8, T=2048, D=512), chunked, bf16 MFMA, fp32 acc.
// R6: five launches, prefix fused into Mt-GEMM, G+den fused into y.
//   k_pre   : bf16(x) + W^T transposes                          (4352 blocks)
//   k8_qkvt : q | kk + Kt^T(+zsum) | Vt^T  (core8h)             (768 blocks)
//   k8_mtst : St = exclusive-chunk-prefix(Vt_c Kt_c^T) fused    (256 blocks)
//   k8_y    : G=tril(QK^T)->LDS, den in-block, y=(QSt^T+GVt^T)/den (256 blocks, 160KB LDS)
//   k8_out  : out = y Wp^T (fp32)                               (256 blocks)
// All GEMMs are C = A * B^T with A:[M][K], B:[N][K] row-major bf16.

typedef __attribute__((ext_vector_type(4))) float f32x4;
typedef __attribute__((ext_vector_type(8))) __bf16 bf16x8;
typedef __attribute__((ext_vector_type(8))) unsigned short ushort8;

// ---- ws layout (byte offsets) ----
constexpr size_t OFF_XB  = 0;                  // bf16 [16384][512]
constexpr size_t OFF_WT  = OFF_XB + 16777216;  // bf16 4x [512][512] (WqT,WkT,WvT,WpT)
constexpr size_t OFF_Q   = OFF_WT + 2097152;   // bf16 [16384][512]
constexpr size_t OFF_KK  = OFF_Q  + 16777216;  // bf16 [16384][512]
constexpr size_t OFF_KT  = OFF_KK + 16777216;  // bf16 [512][16384]
constexpr size_t OFF_VT  = OFF_KT + 16777216;  // bf16 [512][16384]
constexpr size_t OFF_MT  = OFF_VT + 16777216;  // bf16 [64][512][512] St (prefixed)
constexpr size_t OFF_Y   = OFF_MT + 33554432;  // bf16 [16384][512]
constexpr size_t OFF_ZP  = OFF_Y  + 16777216;  // f32  [128][512] half-chunk col sums of kk
constexpr size_t WS_NEED = OFF_ZP + 262144;

__device__ __forceinline__ unsigned short bfbits(float f) {
  __bf16 h = (__bf16)f;
  return __builtin_bit_cast(unsigned short, h);
}
__device__ __forceinline__ float bff(unsigned short u) {
  return (float)__builtin_bit_cast(__bf16, u);
}

__device__ __forceinline__ void gload16(const void* g, void* l) {
  __builtin_amdgcn_global_load_lds((const __attribute__((address_space(1))) void*)g,
                                   (__attribute__((address_space(3))) void*)l, 16, 0, 0);
}

// Stage one 128-row x 64-col bf16 half-tile (16 KiB) with 512 threads.
// LDS dest linear; global source pre-swizzled with byte ^= ((row&7)<<4),
// matching frag_at's read-side swizzle.
__device__ __forceinline__ void stage_half(const char* gRow0, size_t ld2, int k0b,
                                           char* ldsHalf, int w, int lane) {
#pragma unroll
  for (int i = 0; i < 2; ++i) {
    int L = (w << 10) + (lane << 4) + (i << 13);
    int r = L >> 7;
    int cb = (L & 127) ^ ((r & 7) << 4);
    gload16(gRow0 + (size_t)r * ld2 + k0b + cb, ldsHalf + (w << 10) + (i << 13));
  }
}

// Stage a 64-row x 64-col tile (8 KiB), 512 threads, one gload16 each.
__device__ __forceinline__ void stage_q64(const char* gRow0, size_t ld2, int k0b,
                                          char* lds, int tid) {
  int L = tid << 4;
  int r = L >> 7;
  int cb = (L & 127) ^ ((r & 7) << 4);
  gload16(gRow0 + (size_t)r * ld2 + k0b + cb, lds + L);
}

__device__ __forceinline__ const bf16x8* frag_at(const char* halfBase, int rowInHalf,
                                                 int colByte) {
  int lin = (rowInHalf << 7) + colByte;
  lin ^= (rowInHalf & 7) << 4;
  return (const bf16x8*)(halfBase + lin);
}

// ======================= 128x256 8-wave 4-phase core =======================
#define QUADH(mh, nh)                                                                  \
  _Pragma("unroll") for (int mm = 0; mm < 2; ++mm)                                     \
  _Pragma("unroll") for (int nn = 0; nn < 2; ++nn)                                     \
  _Pragma("unroll") for (int s = 0; s < 2; ++s)                                        \
      acc[(mh)*2 + mm][(nh)*2 + nn] = __builtin_amdgcn_mfma_f32_16x16x32_bf16(         \
          af[(mh)*2 + mm][s], bg[(nh)*2 + nn][s], acc[(mh)*2 + mm][(nh)*2 + nn], 0, 0, 0);

#define PHASE_TAILH(MH, NH)                                      \
  __builtin_amdgcn_s_barrier();                                  \
  asm volatile("s_waitcnt lgkmcnt(0)" ::: "memory");             \
  __builtin_amdgcn_sched_barrier(0);                             \
  __builtin_amdgcn_s_setprio(1);                                 \
  QUADH(MH, NH);                                                 \
  __builtin_amdgcn_s_setprio(0);                                 \
  __builtin_amdgcn_s_barrier();

// LDS: sA = 2 buf x 16 KB, sB = 2 buf x 32 KB.
__device__ __forceinline__ void core8h(const char* Ab, size_t lda2, const char* Bb,
                                       size_t ldb2, int nt, char* sA, char* sB,
                                       f32x4 (&acc)[4][4], int w, int lane) {
  const int wr = w >> 2, wc = w & 3;
  const int fr = lane & 15, foB = (lane >> 4) << 4;
  const int brow = (wc & 1) << 6;
  const char* gB1 = Bb + (size_t)128 * ldb2;
  bf16x8 af[4][2], bg[4][2];

  stage_half(Ab, lda2, 0, sA + 0, w, lane);
  stage_half(Bb, ldb2, 0, sB + 0, w, lane);
  stage_half(gB1, ldb2, 0, sB + 16384, w, lane);
  if (nt > 1) {
    stage_half(Ab, lda2, 128, sA + 16384, w, lane);
    asm volatile("s_waitcnt vmcnt(2)" ::: "memory");
  } else {
    asm volatile("s_waitcnt vmcnt(0)" ::: "memory");
  }
  __builtin_amdgcn_sched_barrier(0);
  __builtin_amdgcn_s_barrier();

  for (int t = 0; t < nt; ++t) {
    const int buf = t & 1;
    const char* cA = sA + buf * 16384;
    const char* cB = sB + buf * 32768 + (wc >> 1) * 16384;
    char* nA = sA + buf * 16384;
    char* nB = sB + (buf ^ 1) * 32768;
    const int kb1 = (t + 1) << 7, kb2 = (t + 2) << 7;
    const bool stB = (t + 1 < nt), stA = (t + 2 < nt);

#pragma unroll
    for (int m = 0; m < 2; ++m)
#pragma unroll
      for (int s = 0; s < 2; ++s)
        af[m][s] = *frag_at(cA, wr * 64 + m * 16 + fr, s * 64 + foB);
#pragma unroll
    for (int n = 0; n < 2; ++n)
#pragma unroll
      for (int s = 0; s < 2; ++s)
        bg[n][s] = *frag_at(cB, brow + n * 16 + fr, s * 64 + foB);
    if (stB) stage_half(Bb, ldb2, kb1, nB + 0, w, lane);
    PHASE_TAILH(0, 0)

#pragma unroll
    for (int m = 2; m < 4; ++m)
#pragma unroll
      for (int s = 0; s < 2; ++s)
        af[m][s] = *frag_at(cA, wr * 64 + m * 16 + fr, s * 64 + foB);
    if (stB) stage_half(gB1, ldb2, kb1, nB + 16384, w, lane);
    PHASE_TAILH(1, 0)

#pragma unroll
    for (int n = 2; n < 4; ++n)
#pragma unroll
      for (int s = 0; s < 2; ++s)
        bg[n][s] = *frag_at(cB, brow + n * 16 + fr, s * 64 + foB);
    if (stA) stage_half(Ab, lda2, kb2, nA, w, lane);
    PHASE_TAILH(0, 1)

    if (t < nt - 1) {
      if (stA) {
        asm volatile("s_waitcnt vmcnt(2)" ::: "memory");
      } else {
        asm volatile("s_waitcnt vmcnt(0)" ::: "memory");
      }
      __builtin_amdgcn_sched_barrier(0);
    }
    PHASE_TAILH(1, 1)
  }
}

// ---- B-only-staging variant: A fixed in LDS (sG, 16 KB per K-tile) ----
__device__ __forceinline__ void core8h_ldsA(const char* sG, const char* Bb, size_t ldb2,
                                            int nt, char* sB, f32x4 (&acc)[4][4],
                                            int w, int lane) {
  const int wr = w >> 2, wc = w & 3;
  const int fr = lane & 15, foB = (lane >> 4) << 4;
  const int brow = (wc & 1) << 6;
  const char* gB1 = Bb + (size_t)128 * ldb2;
  bf16x8 af[4][2], bg[4][2];

  stage_half(Bb, ldb2, 0, sB + 0, w, lane);
  stage_half(gB1, ldb2, 0, sB + 16384, w, lane);
  asm volatile("s_waitcnt vmcnt(0)" ::: "memory");
  __builtin_amdgcn_sched_barrier(0);
  __builtin_amdgcn_s_barrier();

  for (int t = 0; t < nt; ++t) {
    const int buf = t & 1;
    const char* cA = sG + t * 16384;
    const char* cB = sB + buf * 32768 + (wc >> 1) * 16384;
    char* nB = sB + (buf ^ 1) * 32768;
    if (t + 1 < nt) {
      stage_half(Bb, ldb2, (t + 1) << 7, nB + 0, w, lane);
      stage_half(gB1, ldb2, (t + 1) << 7, nB + 16384, w, lane);
    }
#pragma unroll
    for (int m = 0; m < 4; ++m)
#pragma unroll
      for (int s = 0; s < 2; ++s)
        af[m][s] = *frag_at(cA, wr * 64 + m * 16 + fr, s * 64 + foB);
#pragma unroll
    for (int n = 0; n < 4; ++n)
#pragma unroll
      for (int s = 0; s < 2; ++s)
        bg[n][s] = *frag_at(cB, brow + n * 16 + fr, s * 64 + foB);
    asm volatile("s_waitcnt lgkmcnt(0)" ::: "memory");
    __builtin_amdgcn_sched_barrier(0);
    __builtin_amdgcn_s_setprio(1);
#pragma unroll
    for (int m = 0; m < 4; ++m)
#pragma unroll
      for (int n = 0; n < 4; ++n)
#pragma unroll
        for (int s = 0; s < 2; ++s)
          acc[m][n] = __builtin_amdgcn_mfma_f32_16x16x32_bf16(af[m][s], bg[n][s],
                                                              acc[m][n], 0, 0, 0);
    __builtin_amdgcn_s_setprio(0);
    if (t + 1 < nt) {
      asm volatile("s_waitcnt vmcnt(0)" ::: "memory");
      __builtin_amdgcn_sched_barrier(0);
      __builtin_amdgcn_s_barrier();
    }
  }
}

#define ACC4_INIT                                    \
  f32x4 acc[4][4];                                   \
  _Pragma("unroll") for (int m_ = 0; m_ < 4; ++m_)   \
  _Pragma("unroll") for (int n_ = 0; n_ < 4; ++n_)   \
      acc[m_][n_] = f32x4{0.f, 0.f, 0.f, 0.f};

#define ACC4_ZERO                                    \
  _Pragma("unroll") for (int m_ = 0; m_ < 4; ++m_)   \
  _Pragma("unroll") for (int n_ = 0; n_ < 4; ++n_)   \
      acc[m_][n_] = f32x4{0.f, 0.f, 0.f, 0.f};

// ---- q | kk+Kt^T(+zsum halves) | Vt^T : 768 blocks, XCD-swizzled ----
__global__ __launch_bounds__(512, 2) void k8_qkvt(const ushort* __restrict__ xb,
                                                  const ushort* __restrict__ wt,
                                                  ushort* __restrict__ qb,
                                                  ushort* __restrict__ kkb,
                                                  ushort* __restrict__ Kt,
                                                  ushort* __restrict__ Vt,
                                                  float* __restrict__ zsumH) {
  extern __shared__ char smem[];
  const int o = blockIdx.x;
  const int wg = (o & 7) * 96 + (o >> 3);  // bijective: 768 % 8 == 0
  const int mt = wg / 6, r6 = wg % 6, z = r6 >> 1, ct = r6 & 1;
  const int tid = threadIdx.x, w = tid >> 6, lane = tid & 63;
  const ushort* wsel = wt + (z == 0 ? 0 : (z == 1 ? 262144 : 524288));
  const ushort* A = xb + (size_t)mt * 128 * 512;
  const ushort* Bp = wsel + (size_t)ct * 256 * 512;
  ACC4_INIT
  core8h((const char*)A, 1024, (const char*)Bp, 1024, 8, smem, smem + 32768, acc, w, lane);
  const int wr = w >> 2, wc = w & 3, fr = lane & 15, q4 = (lane >> 4) << 2;
  const size_t row0 = (size_t)mt * 128 + wr * 64;  // t
  const size_t col0 = (size_t)ct * 256 + wc * 64;  // d
  if (z == 0) {
#pragma unroll
    for (int m = 0; m < 4; ++m)
#pragma unroll
      for (int n = 0; n < 4; ++n)
#pragma unroll
        for (int r = 0; r < 4; ++r) {
          float v = acc[m][n][r];
          v = v > 0.f ? v + 1.f : __expf(v);
          qb[(row0 + m * 16 + q4 + r) * 512 + col0 + n * 16 + fr] = bfbits(v);
        }
  } else if (z == 2) {
#pragma unroll
    for (int m = 0; m < 4; ++m)
#pragma unroll
      for (int n = 0; n < 4; ++n) {
        ushort4 ov;
        ov.x = bfbits(acc[m][n][0]);
        ov.y = bfbits(acc[m][n][1]);
        ov.z = bfbits(acc[m][n][2]);
        ov.w = bfbits(acc[m][n][3]);
        *(ushort4*)&Vt[(col0 + n * 16 + fr) * 16384 + row0 + m * 16 + q4] = ov;
      }
  } else {  // kk normal + Kt transposed + half-chunk col sums
    float zs[4] = {0.f, 0.f, 0.f, 0.f};
#pragma unroll
    for (int m = 0; m < 4; ++m)
#pragma unroll
      for (int n = 0; n < 4; ++n) {
        float ph[4];
#pragma unroll
        for (int r = 0; r < 4; ++r) {
          float v = acc[m][n][r];
          ph[r] = v > 0.f ? v + 1.f : __expf(v);
          kkb[(row0 + m * 16 + q4 + r) * 512 + col0 + n * 16 + fr] = bfbits(ph[r]);
          zs[n] += ph[r];
        }
        ushort4 ov;
        ov.x = bfbits(ph[0]); ov.y = bfbits(ph[1]); ov.z = bfbits(ph[2]); ov.w = bfbits(ph[3]);
        *(ushort4*)&Kt[(col0 + n * 16 + fr) * 16384 + row0 + m * 16 + q4] = ov;
      }
#pragma unroll
    for (int n = 0; n < 4; ++n) {
      zs[n] += __shfl_xor(zs[n], 16, 64);
      zs[n] += __shfl_xor(zs[n], 32, 64);
    }
    float* zbuf = (float*)smem;  // safe: core8h ended with barrier, all reads drained
    if (lane < 16) {
#pragma unroll
      for (int n = 0; n < 4; ++n) zbuf[wr * 256 + wc * 64 + n * 16 + fr] = zs[n];
    }
    __syncthreads();
    if (tid < 256)
      zsumH[(size_t)mt * 512 + ct * 256 + tid] = zbuf[tid] + zbuf[256 + tid];
  }
}

// ---- St = exclusive chunk prefix of Vt_c Kt_c^T, fused (per-tile chunk loop) ----
// Block = one 128(e) x 64(d) tile of one batch; loops c=0..7: write St_c, then acc += M_c.
// 8 waves 2x4: wave 64 rows x 16 cols; acc[4] f32x4. LDS 48 KB static.
__global__ __launch_bounds__(512, 2) void k8_mtst(const ushort* __restrict__ Kt,
                                                  const ushort* __restrict__ Vt,
                                                  ushort* __restrict__ Mt) {
  __shared__ __align__(16) char smem[49152];  // A 2x16K @0, B 2x8K @32768
  const int o = blockIdx.x;
  const int wg = (o & 7) * 32 + (o >> 3);
  const int et = wg >> 6, b = (wg >> 3) & 7, dt = wg & 7;
  const int tid = threadIdx.x, w = tid >> 6, lane = tid & 63;
  const int wr = w >> 2, wc = w & 3, fr = lane & 15;
  const int foB = (lane >> 4) << 4, q4 = (lane >> 4) << 2;
  const char* Ab = (const char*)(Vt + (size_t)et * 128 * 16384 + b * 2048);
  const char* Bb = (const char*)(Kt + (size_t)dt * 64 * 16384 + b * 2048);
  f32x4 acc[4];
#pragma unroll
  for (int m = 0; m < 4; ++m) acc[m] = f32x4{0.f, 0.f, 0.f, 0.f};

  stage_half(Ab, 32768, 0, smem, w, lane);
  stage_q64(Bb, 32768, 0, smem + 32768, tid);
  asm volatile("s_waitcnt vmcnt(0)" ::: "memory");
  __builtin_amdgcn_sched_barrier(0);
  __builtin_amdgcn_s_barrier();

  const int colg = dt * 64 + wc * 16 + fr;
  for (int kk = 0; kk < 32; ++kk) {
    const int c = kk >> 2, buf = kk & 1;
    if ((kk & 3) == 0) {  // write St_c = prefix before chunk c
      ushort* Sc = Mt + (size_t)(b * 8 + c) * 262144 + colg;
#pragma unroll
      for (int m = 0; m < 4; ++m)
#pragma unroll
        for (int r = 0; r < 4; ++r)
          Sc[(size_t)(et * 128 + wr * 64 + m * 16 + q4 + r) * 512] = bfbits(acc[m][r]);
      (void)c;
    }
    if (kk + 1 < 32) {
      const int k0b = ((kk + 1) >> 2) * 512 + ((kk + 1) & 3) * 128;
      stage_half(Ab, 32768, k0b, smem + ((buf ^ 1) << 14), w, lane);
      stage_q64(Bb, 32768, k0b, smem + 32768 + ((buf ^ 1) << 13), tid);
    }
    const char* cA = smem + (buf << 14);
    const char* cB = smem + 32768 + (buf << 13);
    bf16x8 af[4][2], bg[2];
#pragma unroll
    for (int m = 0; m < 4; ++m)
#pragma unroll
      for (int s = 0; s < 2; ++s)
        af[m][s] = *frag_at(cA, wr * 64 + m * 16 + fr, s * 64 + foB);
#pragma unroll
    for (int s = 0; s < 2; ++s) bg[s] = *frag_at(cB, wc * 16 + fr, s * 64 + foB);
    asm volatile("s_waitcnt lgkmcnt(0)" ::: "memory");
    __builtin_amdgcn_sched_barrier(0);
    __builtin_amdgcn_s_setprio(1);
#pragma unroll
    for (int m = 0; m < 4; ++m)
#pragma unroll
      for (int s = 0; s < 2; ++s)
        acc[m] = __builtin_amdgcn_mfma_f32_16x16x32_bf16(af[m][s], bg[s], acc[m], 0, 0, 0);
    __builtin_amdgcn_s_setprio(0);
    asm volatile("s_waitcnt vmcnt(0)" ::: "memory");
    __builtin_amdgcn_sched_barrier(0);
    __builtin_amdgcn_s_barrier();
  }
}

// ---- y uber-kernel: G(LDS) + den in-block + y = (Q St^T + G Vt^T)/den ----
// LDS 160 KB: [0,64K) G 4 halves; [64K,96K) A-dbuf (+ red/zpl/den scratch);
// [96K,160K) B-dbuf.
__global__ __launch_bounds__(512, 2) void k8_y(const ushort* __restrict__ qb,
                                               const ushort* __restrict__ kkb,
                                               const ushort* __restrict__ St,
                                               const ushort* __restrict__ Vt,
                                               const float* __restrict__ zsumH,
                                               ushort* __restrict__ Y) {
  extern __shared__ char smem[];
  const int o = blockIdx.x;
  const int wg = (o & 7) * 32 + (o >> 3);
  const int bc = wg >> 2, rh = (wg >> 1) & 1, ch = wg & 1;
  const int b = bc >> 3, c = bc & 7;
  const int tid = threadIdx.x, w = tid >> 6, lane = tid & 63;
  const int wr = w >> 2, wc = w & 3, fr = lane & 15, q4 = (lane >> 4) << 2;
  char* sA = smem + 65536;
  char* sB = smem + 98304;
  const char* qptr = (const char*)(qb + (size_t)bc * 131072 + (size_t)rh * 65536);

  // --- GEMM_G: G-tile = Q[128] kk^T[256], K=512 ---
  ACC4_INIT
  core8h(qptr, 1024, (const char*)(kkb + (size_t)bc * 131072), 1024, 8, sA, sB, acc, w, lane);

  // --- mask tril, rowsum, write G -> LDS (wave wc owns half wc) ---
  float rs[4][4];
#pragma unroll
  for (int m = 0; m < 4; ++m)
#pragma unroll
    for (int r = 0; r < 4; ++r) rs[m][r] = 0.f;
#pragma unroll
  for (int m = 0; m < 4; ++m)
#pragma unroll
    for (int n = 0; n < 4; ++n)
#pragma unroll
      for (int r = 0; r < 4; ++r) {
        int rowL = wr * 64 + m * 16 + q4 + r;        // 0..127
        int col = wc * 64 + n * 16 + fr;             // 0..255
        float v = (col <= rh * 128 + rowL) ? acc[m][n][r] : 0.f;
        rs[m][r] += v;
        int byte = (rowL << 7) + ((col & 63) << 1);
        byte ^= (rowL & 7) << 4;
        *(__bf16*)(smem + (wc << 14) + byte) = (__bf16)v;
      }
#pragma unroll
  for (int m = 0; m < 4; ++m)
#pragma unroll
    for (int r = 0; r < 4; ++r) {
      rs[m][r] += __shfl_xor(rs[m][r], 1, 64);
      rs[m][r] += __shfl_xor(rs[m][r], 2, 64);
      rs[m][r] += __shfl_xor(rs[m][r], 4, 64);
      rs[m][r] += __shfl_xor(rs[m][r], 8, 64);
    }
  float* red = (float*)sA;        // [4 wc][128]
  float* zpl = red + 512;         // [512]
  float* dend = zpl + 512;        // [128]
  if (fr == 0) {
#pragma unroll
    for (int m = 0; m < 4; ++m)
#pragma unroll
      for (int r = 0; r < 4; ++r) red[wc * 128 + wr * 64 + m * 16 + q4 + r] = rs[m][r];
  }
  {  // zpre[d] for this chunk
    float a = 0.f;
    for (int cp = 0; cp < c; ++cp)
      a += zsumH[(size_t)((b * 8 + cp) * 2) * 512 + tid] +
           zsumH[(size_t)((b * 8 + cp) * 2 + 1) * 512 + tid];
    zpl[tid] = a;
  }
  __syncthreads();
  {  // den: 4 threads per row
    int rl = tid >> 2, quarter = tid & 3;
    int trow = bc * 256 + rh * 128 + rl;
    const ushort* qrow = qb + (size_t)trow * 512 + quarter * 128;
    const float* zq = zpl + quarter * 128;
    float s = 0.f;
    for (int j = 0; j < 128; j += 8) {
      ushort8 qv = *(const ushort8*)&qrow[j];
#pragma unroll
      for (int u = 0; u < 8; ++u) s = fmaf(bff(qv[u]), zq[j + u], s);
    }
    s += __shfl_xor(s, 1, 64);
    s += __shfl_xor(s, 2, 64);
    if (quarter == 0)
      dend[rl] = s + red[rl] + red[128 + rl] + red[256 + rl] + red[384 + rl] + 1e-6f;
  }
  __syncthreads();
  float dinv[4][4];
#pragma unroll
  for (int m = 0; m < 4; ++m)
#pragma unroll
    for (int r = 0; r < 4; ++r) dinv[m][r] = 1.f / dend[wr * 64 + m * 16 + q4 + r];
  __syncthreads();  // scratch reads done before GEMM1 overwrites A-dbuf

  // --- GEMM1: Q St^T (K=512) + GEMM2: G Vt^T (K = rh?256:128, A from LDS) ---
  ACC4_ZERO
  core8h(qptr, 1024, (const char*)(St + (size_t)bc * 262144 + (size_t)ch * 131072), 1024, 8,
         sA, sB, acc, w, lane);
  core8h_ldsA(smem, (const char*)(Vt + (size_t)ch * 256 * 16384 + (size_t)bc * 256), 32768,
              rh ? 4 : 2, sB, acc, w, lane);

#pragma unroll
  for (int m = 0; m < 4; ++m)
#pragma unroll
    for (int n = 0; n < 4; ++n)
#pragma unroll
      for (int r = 0; r < 4; ++r) {
        size_t row = (size_t)bc * 256 + rh * 128 + wr * 64 + m * 16 + q4 + r;
        size_t col = (size_t)ch * 256 + wc * 64 + n * 16 + fr;
        Y[row * 512 + col] = bfbits(acc[m][n][r] * dinv[m][r]);
      }
}

// ---- out = Y WpT^T (fp32) : 256 blocks ----
__global__ __launch_bounds__(512, 2) void k8_out(const ushort* __restrict__ Y,
                                                 const ushort* __restrict__ wt,
                                                 float* __restrict__ out) {
  extern __shared__ char smem[];
  const int o = blockIdx.x;
  const int wg = (o & 7) * 32 + (o >> 3);
  const int mt = wg >> 1, ct = wg & 1;
  const int tid = threadIdx.x, w = tid >> 6, lane = tid & 63;
  ACC4_INIT
  core8h((const char*)(Y + (size_t)mt * 65536), 1024,
         (const char*)(wt + 786432 + (size_t)ct * 131072), 1024, 8,
         smem, smem + 32768, acc, w, lane);
  const int wr = w >> 2, wc = w & 3, fr = lane & 15, q4 = (lane >> 4) << 2;
  const size_t row0 = (size_t)mt * 128 + wr * 64;
  const size_t col0 = (size_t)ct * 256 + wc * 64;
#pragma unroll
  for (int m = 0; m < 4; ++m)
#pragma unroll
    for (int n = 0; n < 4; ++n)
#pragma unroll
      for (int r = 0; r < 4; ++r)
        out[(row0 + m * 16 + q4 + r) * 512 + col0 + n * 16 + fr] = acc[m][n][r];
}

// ---- x -> bf16 (4096 blocks) + W -> W^T bf16 (256 blocks) ----
__global__ __launch_bounds__(256) void k_pre(const float* __restrict__ x,
                                             const float* __restrict__ Wq,
                                             const float* __restrict__ Wk,
                                             const float* __restrict__ Wv,
                                             const float* __restrict__ Wp,
                                             ushort* __restrict__ xb,
                                             ushort* __restrict__ wt) {
  __shared__ float tile[64][65];
  if (blockIdx.x < 4096) {
    size_t i = ((size_t)blockIdx.x * 256 + threadIdx.x) * 8;
    float4 f0 = *(const float4*)&x[i], f1 = *(const float4*)&x[i + 4];
    ushort8 ov;
    ov[0] = bfbits(f0.x); ov[1] = bfbits(f0.y); ov[2] = bfbits(f0.z); ov[3] = bfbits(f0.w);
    ov[4] = bfbits(f1.x); ov[5] = bfbits(f1.y); ov[6] = bfbits(f1.z); ov[7] = bfbits(f1.w);
    *(ushort8*)&xb[i] = ov;
  } else {
    const int g = blockIdx.x - 4096;
    const int bz = g >> 6, rem = g & 63, bxw = rem >> 3, byw = rem & 7;
    const float* src = bz == 0 ? Wq : bz == 1 ? Wk : bz == 2 ? Wv : Wp;
    ushort* dst = wt + (size_t)bz * 262144;
    const int d0 = bxw * 64, n0 = byw * 64;
    const int tr = threadIdx.x >> 4, tc = (threadIdx.x & 15) << 2;
#pragma unroll
    for (int it = 0; it < 4; ++it) {
      float4 f = *(const float4*)&src[(size_t)(d0 + it * 16 + tr) * 512 + n0 + tc];
      tile[it * 16 + tr][tc + 0] = f.x;
      tile[it * 16 + tr][tc + 1] = f.y;
      tile[it * 16 + tr][tc + 2] = f.z;
      tile[it * 16 + tr][tc + 3] = f.w;
    }
    __syncthreads();
#pragma unroll
    for (int it = 0; it < 4; ++it) {
      int n = it * 16 + tr;
      ushort4 ov;
      ov.x = bfbits(tile[tc + 0][n]);
      ov.y = bfbits(tile[tc + 1][n]);
      ov.z = bfbits(tile[tc + 2][n]);
      ov.w = bfbits(tile[tc + 3][n]);
      *(ushort4*)&dst[(size_t)(n0 + n) * 512 + d0 + tc] = ov;
    }
  }
}

extern "C" void kernel_launch(void* const* d_in, const int* in_sizes, int n_in,
                              void* d_out, int out_size, void* d_ws, size_t ws_size,
                              hipStream_t stream) {
  const float* x  = (const float*)d_in[0];
  const float* Wq = (const float*)d_in[1];
  const float* Wk = (const float*)d_in[2];
  const float* Wv = (const float*)d_in[3];
  const float* Wp = (const float*)d_in[4];
  float* out = (float*)d_out;
  char* ws8 = (char*)d_ws;
  if (ws_size < WS_NEED) return;

  ushort* xb  = (ushort*)(ws8 + OFF_XB);
  ushort* wt  = (ushort*)(ws8 + OFF_WT);
  ushort* qb  = (ushort*)(ws8 + OFF_Q);
  ushort* kkb = (ushort*)(ws8 + OFF_KK);
  ushort* Kt  = (ushort*)(ws8 + OFF_KT);
  ushort* Vt  = (ushort*)(ws8 + OFF_VT);
  ushort* Mt  = (ushort*)(ws8 + OFF_MT);
  ushort* Y   = (ushort*)(ws8 + OFF_Y);
  float*  zpH = (float*)(ws8 + OFF_ZP);

  constexpr int SMEM_H = 98304, SMEM_Y = 163840;
  hipFuncSetAttribute((const void*)k8_qkvt, hipFuncAttributeMaxDynamicSharedMemorySize, SMEM_H);
  hipFuncSetAttribute((const void*)k8_y,    hipFuncAttributeMaxDynamicSharedMemorySize, SMEM_Y);
  hipFuncSetAttribute((const void*)k8_out,  hipFuncAttributeMaxDynamicSharedMemorySize, SMEM_H);

  k_pre<<<4352, 256, 0, stream>>>(x, Wq, Wk, Wv, Wp, xb, wt);
  k8_qkvt<<<768, 512, SMEM_H, stream>>>(xb, wt, qb, kkb, Kt, Vt, zpH);
  k8_mtst<<<256, 512, 0, stream>>>(Kt, Vt, Mt);
  k8_y<<<256, 512, SMEM_Y, stream>>>(qb, kkb, Mt, Vt, zpH, Y);
  k8_out<<<256, 512, SMEM_H, stream>>>(Y, wt, out);
}